// Round 4
// baseline (1841.553 us; speedup 1.0000x reference)
//
#include <hip/hip_runtime.h>

#define NN 100000
#define En 400000
#define Gn 2000
#define GRID 2048

typedef unsigned short u16;
typedef unsigned int u32;
typedef __bf16 bf16x8 __attribute__((ext_vector_type(8)));
typedef float f32x4 __attribute__((ext_vector_type(4)));

__device__ __forceinline__ u16 f2bf(float f) {
  union { float f; u32 u; } v; v.f = f;
  return (u16)((v.u + 0x7FFFu + ((v.u >> 16) & 1u)) >> 16);
}
__device__ __forceinline__ float bf2f(u16 h) {
  union { u32 u; float f; } v; v.u = ((u32)h) << 16;
  return v.f;
}

// barrier that drains only LDS ops (global loads/atomics stay in flight)
__device__ __forceinline__ void lds_barrier() {
  asm volatile("s_waitcnt lgkmcnt(0)\ns_barrier" ::: "memory");
}
__device__ __forceinline__ void lds_wave_fence() {
  asm volatile("s_waitcnt lgkmcnt(0)" ::: "memory");
}

#define MFMA16(a, b, c) __builtin_amdgcn_mfma_f32_16x16x32_bf16(a, b, c, 0, 0, 0)

// ---------------- prep kernels ----------------

__global__ __launch_bounds__(256) void k_convert(const float* __restrict__ src,
                                                 u16* __restrict__ dst, int n) {
  int i = blockIdx.x * 256 + threadIdx.x;
  if (i < n) dst[i] = f2bf(src[i]);
}

// We2 [3][128][428] -> bf16 padded [3][128][448]
__global__ __launch_bounds__(256) void k_pad_we2(const float* __restrict__ We2,
                                                 u16* __restrict__ dst) {
  int i = blockIdx.x * 256 + threadIdx.x;
  if (i >= 3 * 128 * 448) return;
  int l = i / 57344;
  int r = i - l * 57344;
  int row = r / 448;
  int k = r - row * 448;
  float v = (k < 428) ? We2[l * 54784 + row * 428 + k] : 0.f;
  dst[i] = f2bf(v);
}

// R = We1[:, :, 128:] [3][428][300] -> bf16 padded [3][448][320]
__global__ __launch_bounds__(256) void k_pad_R(const float* __restrict__ We1,
                                               u16* __restrict__ dst) {
  int i = blockIdx.x * 256 + threadIdx.x;
  if (i >= 3 * 448 * 320) return;
  int l = i / 143360;
  int r = i - l * 143360;
  int row = r / 320;
  int k = r - row * 320;
  float v = 0.f;
  if (row < 428 && k < 300) v = We1[(size_t)l * 183184 + row * 428 + 128 + k];
  dst[i] = f2bf(v);
}

// T2[l][t][j] = edge_emb[t]·We1[l][j][:128] + be1[l][j]   bf16 [3][400][448]
__global__ __launch_bounds__(256) void k_t2(const float* __restrict__ edge_emb,
                                            const float* __restrict__ We1,
                                            const float* __restrict__ be1,
                                            u16* __restrict__ T2) {
  int idx = blockIdx.x * 256 + threadIdx.x;
  if (idx >= 3 * 400 * 448) return;
  int l = idx / (400 * 448);
  int r = idx - l * (400 * 448);
  int t = r / 448;
  int j = r - t * 448;
  float s = 0.f;
  if (j < 428) {
    const float4* er = (const float4*)(edge_emb + t * 128);
    const float4* wr = (const float4*)(We1 + (size_t)l * 183184 + j * 428);
#pragma unroll
    for (int d = 0; d < 32; ++d) {
      float4 a = er[d], b = wr[d];
      s += a.x * b.x + a.y * b.y + a.z * b.z + a.w * b.w;
    }
    s += be1[l * 428 + j];
  }
  T2[idx] = f2bf(s);
}

// Dtab[l][g][j] = sum_k rbf_k(g*delta) * R[l][j][k]   bf16 [3][GRID+1][448]
__global__ __launch_bounds__(256) void k_dtab(const u16* __restrict__ Rb,
                                              u16* __restrict__ Dtab) {
  const int tid = threadIdx.x;
  int l = blockIdx.x / (GRID + 1);
  int g = blockIdx.x - l * (GRID + 1);
  float d = (float)g * (30.f / (float)GRID);
  int kc = (int)(d * (299.f / 30.f) + 0.5f);
  int kk0 = min(max(kc - 16, 0), 268);
  __shared__ float sE[32];
  if (tid < 32) {
    float x = d - (float)(kk0 + tid) * (30.f / 299.f);
    sE[tid] = __expf(-x * x * (299.f / 30.f));
  }
  __syncthreads();
  for (int j = tid; j < 448; j += 256) {
    const u16* rr = &Rb[((size_t)l * 448 + j) * 320 + kk0];
    float s = 0.f;
#pragma unroll
    for (int k = 0; k < 32; ++k) s += sE[k] * bf2f(rr[k]);
    Dtab[((size_t)(l * (GRID + 1) + g)) * 448 + j] = f2bf(s);
  }
}

// h[n][:] = node_emb[Z[n]][:]
__global__ __launch_bounds__(256) void k_hinit(const int* __restrict__ Z,
                                               const float* __restrict__ node_emb,
                                               float* __restrict__ h) {
  int idx = blockIdx.x * 256 + threadIdx.x;
  int n = idx >> 5;
  int c = idx & 31;
  ((float4*)h)[idx] = ((const float4*)node_emb)[Z[n] * 32 + c];
}

__global__ __launch_bounds__(256) void k_zero_out(float* __restrict__ out) {
  int i = blockIdx.x * 256 + threadIdx.x;
  if (i < Gn) out[i] = 0.f;
}

// ---------------- node MLP: n2 = relu(h@W1^T+b1)@W2^T+b2  (bf16 out) ----------------

__global__ __launch_bounds__(256) void k_node(const float* __restrict__ h,
                                              const u16* __restrict__ W1,
                                              const float* __restrict__ b1,
                                              const u16* __restrict__ W2,
                                              const float* __restrict__ b2,
                                              u16* __restrict__ n2) {
  __shared__ __align__(16) u16 sH[64 * 136];
  __shared__ __align__(16) u16 sT[64 * 136];
  const int tid = threadIdx.x;
  const int nbase = blockIdx.x * 64;
  for (int i = tid; i < 64 * 128; i += 256) {
    int e = i >> 7, d = i & 127;
    int node = nbase + e;
    float v = (node < NN) ? h[(size_t)node * 128 + d] : 0.f;
    sH[e * 136 + d] = f2bf(v);
  }
  lds_barrier();
  const int lane = tid & 63, wave = tid >> 6;
  const int q = lane >> 4, ln = lane & 15;
  const int nb = wave * 32;

  f32x4 acc[4][2];
#pragma unroll
  for (int m = 0; m < 4; ++m)
#pragma unroll
    for (int n = 0; n < 2; ++n) acc[m][n] = 0.f;
#pragma unroll
  for (int k0 = 0; k0 < 128; k0 += 32) {
    bf16x8 a[4];
#pragma unroll
    for (int m = 0; m < 4; ++m)
      a[m] = *(const bf16x8*)&sH[(m * 16 + ln) * 136 + k0 + q * 8];
#pragma unroll
    for (int n = 0; n < 2; ++n) {
      bf16x8 b = *(const bf16x8*)&W1[(nb + n * 16 + ln) * 128 + k0 + q * 8];
#pragma unroll
      for (int m = 0; m < 4; ++m) acc[m][n] = MFMA16(a[m], b, acc[m][n]);
    }
  }
#pragma unroll
  for (int n = 0; n < 2; ++n) {
    int col = nb + n * 16 + ln;
    float bb = b1[col];
#pragma unroll
    for (int m = 0; m < 4; ++m)
#pragma unroll
      for (int r = 0; r < 4; ++r) {
        int row = m * 16 + q * 4 + r;
        sT[row * 136 + col] = f2bf(fmaxf(acc[m][n][r] + bb, 0.f));
      }
  }
  lds_barrier();

  f32x4 acc2[4][2];
#pragma unroll
  for (int m = 0; m < 4; ++m)
#pragma unroll
    for (int n = 0; n < 2; ++n) acc2[m][n] = 0.f;
#pragma unroll
  for (int k0 = 0; k0 < 128; k0 += 32) {
    bf16x8 a[4];
#pragma unroll
    for (int m = 0; m < 4; ++m)
      a[m] = *(const bf16x8*)&sT[(m * 16 + ln) * 136 + k0 + q * 8];
#pragma unroll
    for (int n = 0; n < 2; ++n) {
      bf16x8 b = *(const bf16x8*)&W2[(nb + n * 16 + ln) * 128 + k0 + q * 8];
#pragma unroll
      for (int m = 0; m < 4; ++m) acc2[m][n] = MFMA16(a[m], b, acc2[m][n]);
    }
  }
#pragma unroll
  for (int n = 0; n < 2; ++n) {
    int col = nb + n * 16 + ln;
    float bb = b2[col];
#pragma unroll
    for (int m = 0; m < 4; ++m)
#pragma unroll
      for (int r = 0; r < 4; ++r) {
        int row = m * 16 + q * 4 + r;
        int node = nbase + row;
        if (node < NN) n2[(size_t)node * 128 + col] = f2bf(acc2[m][n][r] + bb);
      }
  }
}

// ---------------- fused edge kernel (one layer) ----------------
// Barrier-free: each wave owns 32 edges (m=2 tiles) x full 128 out dims
// (n=8 tiles). A-fragments gathered+lerped directly in registers; only
// wave-private LDS transpose between phase 2 and phase 3 (lgkmcnt only).

__global__ __launch_bounds__(256, 4) void k_edge(
    const int* __restrict__ etype, const float* __restrict__ dist,
    const int* __restrict__ src, const int* __restrict__ dstv,
    const u16* __restrict__ T2, const u16* __restrict__ Dtab,
    const u16* __restrict__ We2b, const float* __restrict__ be2,
    const u16* __restrict__ Wcb, const float* __restrict__ bc,
    const u16* __restrict__ n2, float* __restrict__ h) {
  __shared__ __align__(16) u16 sPall[4][32 * 136];

  const int tid = threadIdx.x;
  const int lane = tid & 63, wave = tid >> 6;
  const int q = lane >> 4, ln = lane & 15;
  const int ebase = blockIdx.x * 128 + wave * 32;
  u16* sP = sPall[wave];

  // per-lane A-path edge scalars (edges ebase + mi*16 + ln)
  int aIdx[2], aT2[2];
  float aFr[2];
#pragma unroll
  for (int mi = 0; mi < 2; ++mi) {
    int e = ebase + mi * 16 + ln;
    float d = dist[e];
    float fi = d * ((float)GRID / 30.f);
    int ix = (int)fi;
    aFr[mi] = fi - (float)ix;
    aIdx[mi] = ix * 448;
    aT2[mi] = etype[e] * 448;
  }

  // ---- phase 2: EE = U @ We2^T,  U = relu(T2[et] + lerp(Dtab)) ----
  f32x4 acc[2][8];
#pragma unroll
  for (int mi = 0; mi < 2; ++mi)
#pragma unroll
    for (int n = 0; n < 8; ++n) acc[mi][n] = 0.f;

#pragma unroll 2
  for (int kk = 0; kk < 14; ++kk) {
    const int co = kk * 32 + q * 8;
    bf16x8 a[2];
#pragma unroll
    for (int mi = 0; mi < 2; ++mi) {
      bf16x8 lo = *(const bf16x8*)&Dtab[aIdx[mi] + co];
      bf16x8 hi = *(const bf16x8*)&Dtab[aIdx[mi] + 448 + co];
      bf16x8 t2 = *(const bf16x8*)&T2[aT2[mi] + co];
      float fr = aFr[mi];
#pragma unroll
      for (int j = 0; j < 8; ++j) {
        float l0 = (float)lo[j];
        float v = (float)t2[j] + l0 + fr * ((float)hi[j] - l0);
        a[mi][j] = (__bf16)fmaxf(v, 0.f);
      }
    }
#pragma unroll
    for (int n = 0; n < 8; ++n) {
      bf16x8 b = *(const bf16x8*)&We2b[(n * 16 + ln) * 448 + co];
#pragma unroll
      for (int mi = 0; mi < 2; ++mi) acc[mi][n] = MFMA16(a[mi], b, acc[mi][n]);
    }
  }

  // ---- epilogue 2: P = (EE + be2) * n2[src] -> wave-private sP ----
  int eSrc[2][4];
#pragma unroll
  for (int mi = 0; mi < 2; ++mi)
#pragma unroll
    for (int r = 0; r < 4; ++r) eSrc[mi][r] = src[ebase + mi * 16 + q * 4 + r];
  float be2v[8];
#pragma unroll
  for (int n = 0; n < 8; ++n) be2v[n] = be2[n * 16 + ln];

#pragma unroll
  for (int mi = 0; mi < 2; ++mi) {
    u16 g[8][4];
#pragma unroll
    for (int n = 0; n < 8; ++n)
#pragma unroll
      for (int r = 0; r < 4; ++r)
        g[n][r] = n2[(size_t)eSrc[mi][r] * 128 + n * 16 + ln];
#pragma unroll
    for (int n = 0; n < 8; ++n)
#pragma unroll
      for (int r = 0; r < 4; ++r) {
        float p = (acc[mi][n][r] + be2v[n]) * bf2f(g[n][r]);
        *(__bf16*)&sP[(mi * 16 + q * 4 + r) * 136 + n * 16 + ln] = (__bf16)p;
      }
  }
  lds_wave_fence();  // ds writes -> ds reads, same wave: lgkmcnt only

  // ---- phase 3: m = tanh(P @ Wc^T + bc); h[dst] += m ----
  f32x4 acc2[2][8];
#pragma unroll
  for (int mi = 0; mi < 2; ++mi)
#pragma unroll
    for (int n = 0; n < 8; ++n) acc2[mi][n] = 0.f;
#pragma unroll
  for (int kk = 0; kk < 4; ++kk) {
    const int co = kk * 32 + q * 8;
    bf16x8 a[2];
#pragma unroll
    for (int mi = 0; mi < 2; ++mi)
      a[mi] = *(const bf16x8*)&sP[(mi * 16 + ln) * 136 + co];
#pragma unroll
    for (int n = 0; n < 8; ++n) {
      bf16x8 b = *(const bf16x8*)&Wcb[(n * 16 + ln) * 128 + co];
#pragma unroll
      for (int mi = 0; mi < 2; ++mi) acc2[mi][n] = MFMA16(a[mi], b, acc2[mi][n]);
    }
  }

  int eDst[2][4];
#pragma unroll
  for (int mi = 0; mi < 2; ++mi)
#pragma unroll
    for (int r = 0; r < 4; ++r) eDst[mi][r] = dstv[ebase + mi * 16 + q * 4 + r];
  float bcv[8];
#pragma unroll
  for (int n = 0; n < 8; ++n) bcv[n] = bc[n * 16 + ln];

#pragma unroll
  for (int mi = 0; mi < 2; ++mi)
#pragma unroll
    for (int n = 0; n < 8; ++n)
#pragma unroll
      for (int r = 0; r < 4; ++r) {
        // Pade [3/2] tanh: inputs ~1e-3 scale, err << bf16 ulp
        float x = acc2[mi][n][r] + bcv[n];
        x = fminf(2.f, fmaxf(-2.f, x));
        float x2 = x * x;
        float t = x * (15.f + x2) * __builtin_amdgcn_rcpf(15.f + 6.f * x2);
        unsafeAtomicAdd(&h[(size_t)eDst[mi][r] * 128 + n * 16 + ln], t);
      }
}

// ---------------- readout ----------------

__global__ __launch_bounds__(256) void k_read(const float* __restrict__ h,
                                              const float* __restrict__ Wr1,
                                              const float* __restrict__ br1,
                                              const float* __restrict__ Wr2,
                                              const float* __restrict__ br2,
                                              const int* __restrict__ gid,
                                              float* __restrict__ out) {
  __shared__ __align__(16) u16 sH[64 * 136];
  __shared__ __align__(16) u16 sW[128 * 136];
  __shared__ float sR4[4][64];
  const int tid = threadIdx.x;
  const int nbase = blockIdx.x * 64;
  for (int i = tid; i < 64 * 128; i += 256) {
    int e = i >> 7, d = i & 127;
    int node = nbase + e;
    float v = (node < NN) ? h[(size_t)node * 128 + d] : 0.f;
    sH[e * 136 + d] = f2bf(v);
  }
  for (int i = tid; i < 128 * 128; i += 256) {
    int rr = i >> 7, d = i & 127;
    sW[rr * 136 + d] = f2bf(Wr1[i]);
  }
  lds_barrier();
  const int lane = tid & 63, wave = tid >> 6;
  const int q = lane >> 4, ln = lane & 15;
  const int nb = wave * 32;

  f32x4 acc[4][2];
#pragma unroll
  for (int m = 0; m < 4; ++m)
#pragma unroll
    for (int n = 0; n < 2; ++n) acc[m][n] = 0.f;
#pragma unroll
  for (int k0 = 0; k0 < 128; k0 += 32) {
    bf16x8 a[4];
#pragma unroll
    for (int m = 0; m < 4; ++m)
      a[m] = *(const bf16x8*)&sH[(m * 16 + ln) * 136 + k0 + q * 8];
#pragma unroll
    for (int n = 0; n < 2; ++n) {
      bf16x8 b = *(const bf16x8*)&sW[(nb + n * 16 + ln) * 136 + k0 + q * 8];
#pragma unroll
      for (int m = 0; m < 4; ++m) acc[m][n] = MFMA16(a[m], b, acc[m][n]);
    }
  }
#pragma unroll
  for (int m = 0; m < 4; ++m)
#pragma unroll
    for (int r = 0; r < 4; ++r) {
      float t = 0.f;
#pragma unroll
      for (int n = 0; n < 2; ++n) {
        int col = nb + n * 16 + ln;
        t += fmaxf(acc[m][n][r] + br1[col], 0.f) * Wr2[col];
      }
      t += __shfl_xor(t, 1);
      t += __shfl_xor(t, 2);
      t += __shfl_xor(t, 4);
      t += __shfl_xor(t, 8);
      if (ln == 0) sR4[wave][m * 16 + q * 4 + r] = t;
    }
  lds_barrier();
  if (tid < 64) {
    int node = nbase + tid;
    if (node < NN) {
      float s = sR4[0][tid] + sR4[1][tid] + sR4[2][tid] + sR4[3][tid] + br2[0];
      unsafeAtomicAdd(&out[gid[node]], s);
    }
  }
}

// ---------------- launch ----------------

extern "C" void kernel_launch(void* const* d_in, const int* in_sizes, int n_in,
                              void* d_out, int out_size, void* d_ws, size_t ws_size,
                              hipStream_t stream) {
  const int* Z = (const int*)d_in[0];
  const int* etype = (const int*)d_in[1];
  const float* dist = (const float*)d_in[2];
  const int* src = (const int*)d_in[3];
  const int* dst = (const int*)d_in[4];
  const int* gid = (const int*)d_in[5];
  const float* node_emb = (const float*)d_in[6];
  const float* edge_emb = (const float*)d_in[7];
  const float* Wn1 = (const float*)d_in[8];
  const float* bn1 = (const float*)d_in[9];
  const float* Wn2 = (const float*)d_in[10];
  const float* bn2 = (const float*)d_in[11];
  const float* We1 = (const float*)d_in[12];
  const float* be1 = (const float*)d_in[13];
  const float* We2 = (const float*)d_in[14];
  const float* be2 = (const float*)d_in[15];
  const float* Wc = (const float*)d_in[16];
  const float* bc = (const float*)d_in[17];
  const float* Wr1 = (const float*)d_in[18];
  const float* br1 = (const float*)d_in[19];
  const float* Wr2 = (const float*)d_in[20];
  const float* br2 = (const float*)d_in[21];
  float* out = (float*)d_out;

  char* ws = (char*)d_ws;
  float* h = (float*)(ws);                   // 51,200,000 B
  u16* n2 = (u16*)(ws + 51200000);           // 25,600,000 B
  u16* Rb = (u16*)(ws + 76800000);           //    860,160 B
  u16* We2b = (u16*)(ws + 77660160);         //    344,064 B
  u16* Wcb = (u16*)(ws + 78004224);          //     98,304 B
  u16* Wn1b = (u16*)(ws + 78102528);         //     98,304 B
  u16* Wn2b = (u16*)(ws + 78200832);         //     98,304 B
  u16* T2 = (u16*)(ws + 78299136);           //  1,075,200 B
  u16* Dtab = (u16*)(ws + 79374336);         //  5,507,712 B  (end 84,882,048)

  k_convert<<<192, 256, 0, stream>>>(Wn1, Wn1b, 49152);
  k_convert<<<192, 256, 0, stream>>>(Wn2, Wn2b, 49152);
  k_convert<<<192, 256, 0, stream>>>(Wc, Wcb, 49152);
  k_pad_we2<<<672, 256, 0, stream>>>(We2, We2b);
  k_pad_R<<<1680, 256, 0, stream>>>(We1, Rb);
  k_t2<<<2100, 256, 0, stream>>>(edge_emb, We1, be1, T2);
  k_dtab<<<3 * (GRID + 1), 256, 0, stream>>>(Rb, Dtab);
  k_hinit<<<12500, 256, 0, stream>>>(Z, node_emb, h);
  k_zero_out<<<8, 256, 0, stream>>>(out);

  for (int l = 0; l < 3; ++l) {
    k_node<<<1563, 256, 0, stream>>>(h, Wn1b + l * 16384, bn1 + l * 128,
                                     Wn2b + l * 16384, bn2 + l * 128, n2);
    k_edge<<<3125, 256, 0, stream>>>(etype, dist, src, dst,
                                     T2 + l * 179200, Dtab + (size_t)l * (GRID + 1) * 448,
                                     We2b + l * 57344, be2 + l * 128,
                                     Wcb + l * 16384, bc + l * 128, n2, h);
  }
  k_read<<<1563, 256, 0, stream>>>(h, Wr1, br1, Wr2, br2, gid, out);
}

// Round 5
// 1017.433 us; speedup vs baseline: 1.8100x; 1.8100x over previous
//
#include <hip/hip_runtime.h>

#define NN 100000
#define En 400000
#define Gn 2000
#define GRID 2048

typedef unsigned short u16;
typedef unsigned int u32;
typedef __bf16 bf16x8 __attribute__((ext_vector_type(8)));
typedef float f32x4 __attribute__((ext_vector_type(4)));

__device__ __forceinline__ u16 f2bf(float f) {
  union { float f; u32 u; } v; v.f = f;
  return (u16)((v.u + 0x7FFFu + ((v.u >> 16) & 1u)) >> 16);
}
__device__ __forceinline__ float bf2f(u16 h) {
  union { u32 u; float f; } v; v.u = ((u32)h) << 16;
  return v.f;
}

// barrier that drains only LDS ops (global loads/atomics stay in flight)
__device__ __forceinline__ void lds_barrier() {
  asm volatile("s_waitcnt lgkmcnt(0)\ns_barrier" ::: "memory");
}

#define MFMA16(a, b, c) __builtin_amdgcn_mfma_f32_16x16x32_bf16(a, b, c, 0, 0, 0)

// ---------------- prep kernels ----------------

__global__ __launch_bounds__(256) void k_convert(const float* __restrict__ src,
                                                 u16* __restrict__ dst, int n) {
  int i = blockIdx.x * 256 + threadIdx.x;
  if (i < n) dst[i] = f2bf(src[i]);
}

// We2 [3][128][428] -> bf16 padded [3][128][448]
__global__ __launch_bounds__(256) void k_pad_we2(const float* __restrict__ We2,
                                                 u16* __restrict__ dst) {
  int i = blockIdx.x * 256 + threadIdx.x;
  if (i >= 3 * 128 * 448) return;
  int l = i / 57344;
  int r = i - l * 57344;
  int row = r / 448;
  int k = r - row * 448;
  float v = (k < 428) ? We2[l * 54784 + row * 428 + k] : 0.f;
  dst[i] = f2bf(v);
}

// R = We1[:, :, 128:] [3][428][300] -> bf16 padded [3][448][320]
__global__ __launch_bounds__(256) void k_pad_R(const float* __restrict__ We1,
                                               u16* __restrict__ dst) {
  int i = blockIdx.x * 256 + threadIdx.x;
  if (i >= 3 * 448 * 320) return;
  int l = i / 143360;
  int r = i - l * 143360;
  int row = r / 320;
  int k = r - row * 320;
  float v = 0.f;
  if (row < 428 && k < 300) v = We1[(size_t)l * 183184 + row * 428 + 128 + k];
  dst[i] = f2bf(v);
}

// T2[l][t][j] = edge_emb[t]·We1[l][j][:128] + be1[l][j]   bf16 [3][400][448]
__global__ __launch_bounds__(256) void k_t2(const float* __restrict__ edge_emb,
                                            const float* __restrict__ We1,
                                            const float* __restrict__ be1,
                                            u16* __restrict__ T2) {
  int idx = blockIdx.x * 256 + threadIdx.x;
  if (idx >= 3 * 400 * 448) return;
  int l = idx / (400 * 448);
  int r = idx - l * (400 * 448);
  int t = r / 448;
  int j = r - t * 448;
  float s = 0.f;
  if (j < 428) {
    const float4* er = (const float4*)(edge_emb + t * 128);
    const float4* wr = (const float4*)(We1 + (size_t)l * 183184 + j * 428);
#pragma unroll
    for (int d = 0; d < 32; ++d) {
      float4 a = er[d], b = wr[d];
      s += a.x * b.x + a.y * b.y + a.z * b.z + a.w * b.w;
    }
    s += be1[l * 428 + j];
  }
  T2[idx] = f2bf(s);
}

// Dtab[l][g][j] = sum_k rbf_k(g*delta) * R[l][j][k]   bf16 [3][GRID+1][448]
__global__ __launch_bounds__(256) void k_dtab(const u16* __restrict__ Rb,
                                              u16* __restrict__ Dtab) {
  const int tid = threadIdx.x;
  int l = blockIdx.x / (GRID + 1);
  int g = blockIdx.x - l * (GRID + 1);
  float d = (float)g * (30.f / (float)GRID);
  int kc = (int)(d * (299.f / 30.f) + 0.5f);
  int kk0 = min(max(kc - 16, 0), 268);
  __shared__ float sE[32];
  if (tid < 32) {
    float x = d - (float)(kk0 + tid) * (30.f / 299.f);
    sE[tid] = __expf(-x * x * (299.f / 30.f));
  }
  __syncthreads();
  for (int j = tid; j < 448; j += 256) {
    const u16* rr = &Rb[((size_t)l * 448 + j) * 320 + kk0];
    float s = 0.f;
#pragma unroll
    for (int k = 0; k < 32; ++k) s += sE[k] * bf2f(rr[k]);
    Dtab[((size_t)(l * (GRID + 1) + g)) * 448 + j] = f2bf(s);
  }
}

// h[n][:] = node_emb[Z[n]][:]
__global__ __launch_bounds__(256) void k_hinit(const int* __restrict__ Z,
                                               const float* __restrict__ node_emb,
                                               float* __restrict__ h) {
  int idx = blockIdx.x * 256 + threadIdx.x;
  int n = idx >> 5;
  int c = idx & 31;
  ((float4*)h)[idx] = ((const float4*)node_emb)[Z[n] * 32 + c];
}

__global__ __launch_bounds__(256) void k_zero_out(float* __restrict__ out) {
  int i = blockIdx.x * 256 + threadIdx.x;
  if (i < Gn) out[i] = 0.f;
}

// ---------------- counting sort of edges by dst ----------------

__global__ __launch_bounds__(256) void k_zero32(u32* __restrict__ p, int n) {
  int i = blockIdx.x * 256 + threadIdx.x;
  if (i < n) p[i] = 0u;
}

__global__ __launch_bounds__(256) void k_hist(const int* __restrict__ dstv,
                                              u32* __restrict__ hist) {
  int e = blockIdx.x * 256 + threadIdx.x;
  if (e < En) atomicAdd(&hist[dstv[e]], 1u);
}

// inclusive scan per 1024-block; writes exclusive-within-block + block total
__global__ __launch_bounds__(1024) void k_scan1(const u32* __restrict__ hist,
                                                u32* __restrict__ excl,
                                                u32* __restrict__ part) {
  __shared__ u32 s[1024];
  const int t = threadIdx.x, b = blockIdx.x, i = b * 1024 + t;
  u32 v = (i < NN) ? hist[i] : 0u;
  s[t] = v;
  __syncthreads();
  u32 acc = v;
  for (int off = 1; off < 1024; off <<= 1) {
    u32 add = (t >= off) ? s[t - off] : 0u;
    __syncthreads();
    acc += add;
    s[t] = acc;
    __syncthreads();
  }
  if (i < NN) excl[i] = acc - v;
  if (t == 1023) part[b] = acc;
}

__global__ void k_scan2(u32* __restrict__ part, int n) {
  if (threadIdx.x == 0 && blockIdx.x == 0) {
    u32 run = 0;
    for (int i = 0; i < n; ++i) { u32 t = part[i]; part[i] = run; run += t; }
  }
}

__global__ __launch_bounds__(1024) void k_scan3(const u32* __restrict__ excl,
                                                const u32* __restrict__ part,
                                                u32* __restrict__ cursor) {
  int i = blockIdx.x * 1024 + threadIdx.x;
  if (i < NN) cursor[i] = excl[i] + part[blockIdx.x];
}

__global__ __launch_bounds__(256) void k_scatter(const int* __restrict__ etype,
                                                 const float* __restrict__ dist,
                                                 const int* __restrict__ srcv,
                                                 const int* __restrict__ dstv,
                                                 u32* __restrict__ cursor,
                                                 int4* __restrict__ epack,
                                                 int* __restrict__ edst) {
  int e = blockIdx.x * 256 + threadIdx.x;
  if (e >= En) return;
  int d = dstv[e];
  int pos = (int)atomicAdd(&cursor[d], 1u);
  float fi = dist[e] * ((float)GRID / 30.f);
  int ix = (int)fi;
  epack[pos] = make_int4(srcv[e], etype[e] * 448, ix * 448,
                         __float_as_int(fi - (float)ix));
  edst[pos] = d;
}

// ---------------- node MLP: n2 = relu(h@W1^T+b1)@W2^T+b2  (bf16 out) ----------------

__global__ __launch_bounds__(256) void k_node(const float* __restrict__ h,
                                              const u16* __restrict__ W1,
                                              const float* __restrict__ b1,
                                              const u16* __restrict__ W2,
                                              const float* __restrict__ b2,
                                              u16* __restrict__ n2) {
  __shared__ __align__(16) u16 sH[64 * 136];
  __shared__ __align__(16) u16 sT[64 * 136];
  const int tid = threadIdx.x;
  const int nbase = blockIdx.x * 64;
  for (int i = tid; i < 64 * 128; i += 256) {
    int e = i >> 7, d = i & 127;
    int node = nbase + e;
    float v = (node < NN) ? h[(size_t)node * 128 + d] : 0.f;
    sH[e * 136 + d] = f2bf(v);
  }
  __syncthreads();
  const int lane = tid & 63, wave = tid >> 6;
  const int q = lane >> 4, ln = lane & 15;
  const int nb = wave * 32;

  f32x4 acc[4][2];
#pragma unroll
  for (int m = 0; m < 4; ++m)
#pragma unroll
    for (int n = 0; n < 2; ++n) acc[m][n] = 0.f;
#pragma unroll
  for (int k0 = 0; k0 < 128; k0 += 32) {
    bf16x8 a[4];
#pragma unroll
    for (int m = 0; m < 4; ++m)
      a[m] = *(const bf16x8*)&sH[(m * 16 + ln) * 136 + k0 + q * 8];
#pragma unroll
    for (int n = 0; n < 2; ++n) {
      bf16x8 b = *(const bf16x8*)&W1[(nb + n * 16 + ln) * 128 + k0 + q * 8];
#pragma unroll
      for (int m = 0; m < 4; ++m) acc[m][n] = MFMA16(a[m], b, acc[m][n]);
    }
  }
#pragma unroll
  for (int n = 0; n < 2; ++n) {
    int col = nb + n * 16 + ln;
    float bb = b1[col];
#pragma unroll
    for (int m = 0; m < 4; ++m)
#pragma unroll
      for (int r = 0; r < 4; ++r) {
        int row = m * 16 + q * 4 + r;
        sT[row * 136 + col] = f2bf(fmaxf(acc[m][n][r] + bb, 0.f));
      }
  }
  __syncthreads();

  f32x4 acc2[4][2];
#pragma unroll
  for (int m = 0; m < 4; ++m)
#pragma unroll
    for (int n = 0; n < 2; ++n) acc2[m][n] = 0.f;
#pragma unroll
  for (int k0 = 0; k0 < 128; k0 += 32) {
    bf16x8 a[4];
#pragma unroll
    for (int m = 0; m < 4; ++m)
      a[m] = *(const bf16x8*)&sT[(m * 16 + ln) * 136 + k0 + q * 8];
#pragma unroll
    for (int n = 0; n < 2; ++n) {
      bf16x8 b = *(const bf16x8*)&W2[(nb + n * 16 + ln) * 128 + k0 + q * 8];
#pragma unroll
      for (int m = 0; m < 4; ++m) acc2[m][n] = MFMA16(a[m], b, acc2[m][n]);
    }
  }
#pragma unroll
  for (int n = 0; n < 2; ++n) {
    int col = nb + n * 16 + ln;
    float bb = b2[col];
#pragma unroll
    for (int m = 0; m < 4; ++m)
#pragma unroll
      for (int r = 0; r < 4; ++r) {
        int row = m * 16 + q * 4 + r;
        int node = nbase + row;
        if (node < NN) n2[(size_t)node * 128 + col] = f2bf(acc2[m][n][r] + bb);
      }
  }
}

// ---------------- fused edge kernel (one layer) ----------------
// round-3 chunked pipeline + dst-sorted edges + LDS n2 staging + run-merged atomics
// LDS ~53.7 KB -> 3 blocks/CU

__global__ __launch_bounds__(256, 3) void k_edge(
    const int4* __restrict__ epack, const int* __restrict__ edst,
    const u16* __restrict__ T2, const u16* __restrict__ Dtab,
    const u16* __restrict__ We2b, const float* __restrict__ be2,
    const u16* __restrict__ Wcb, const float* __restrict__ bc,
    const u16* __restrict__ n2, float* __restrict__ h) {
  __shared__ __align__(16) u16 sC[2][64 * 136];  // U K-chunks; sC[0] reused for n2 rows
  __shared__ __align__(16) u16 sP[64 * 136];
  __shared__ int sSrc[64], sDst[64], sT2o[64], sIdx[64];
  __shared__ float sFrac[64];

  const int tid = threadIdx.x;
  const int e0 = blockIdx.x * 64;
  if (tid < 64) {
    int4 p = epack[e0 + tid];
    sSrc[tid] = p.x;
    sT2o[tid] = p.y;
    sIdx[tid] = p.z;
    sFrac[tid] = __int_as_float(p.w);
    sDst[tid] = edst[e0 + tid];
  }
  lds_barrier();

  const int lane = tid & 63, wave = tid >> 6;
  const int q = lane >> 4, ln = lane & 15;
  const int nb = wave * 32;

  f32x4 acc[4][2];
#pragma unroll
  for (int m = 0; m < 4; ++m)
#pragma unroll
    for (int n = 0; n < 2; ++n) acc[m][n] = 0.f;

  auto prefetch128 = [&](int k0, bf16x8* plo, bf16x8* phi, bf16x8* pt2, float* pfr) {
    const int cg = tid & 15, eb = tid >> 4;
    const int col = k0 + cg * 8;
#pragma unroll
    for (int i = 0; i < 4; ++i) {
      int e = eb + i * 16;
      int off = sIdx[e] + col;
      plo[i] = *(const bf16x8*)&Dtab[off];
      phi[i] = *(const bf16x8*)&Dtab[off + 448];
      pt2[i] = *(const bf16x8*)&T2[sT2o[e] + col];
      pfr[i] = sFrac[e];
    }
  };
  auto store128 = [&](u16* buf, const bf16x8* plo, const bf16x8* phi,
                      const bf16x8* pt2, const float* pfr) {
    const int cg = tid & 15, eb = tid >> 4;
#pragma unroll
    for (int i = 0; i < 4; ++i) {
      int e = eb + i * 16;
      bf16x8 o;
#pragma unroll
      for (int j = 0; j < 8; ++j) {
        float l0 = (float)plo[i][j], h0 = (float)phi[i][j];
        float v = (float)pt2[i][j] + l0 + pfr[i] * (h0 - l0);
        o[j] = (__bf16)fmaxf(v, 0.f);
      }
      *(bf16x8*)&buf[e * 136 + cg * 8] = o;
    }
  };
  auto prefetch64 = [&](bf16x8* plo, bf16x8* phi, bf16x8* pt2, float* pfr) {
    const int cg = tid & 7, eb = tid >> 3;
    const int col = 384 + cg * 8;
#pragma unroll
    for (int i = 0; i < 2; ++i) {
      int e = eb + i * 32;
      int off = sIdx[e] + col;
      plo[i] = *(const bf16x8*)&Dtab[off];
      phi[i] = *(const bf16x8*)&Dtab[off + 448];
      pt2[i] = *(const bf16x8*)&T2[sT2o[e] + col];
      pfr[i] = sFrac[e];
    }
  };
  auto store64 = [&](u16* buf, const bf16x8* plo, const bf16x8* phi,
                     const bf16x8* pt2, const float* pfr) {
    const int cg = tid & 7, eb = tid >> 3;
#pragma unroll
    for (int i = 0; i < 2; ++i) {
      int e = eb + i * 32;
      bf16x8 o;
#pragma unroll
      for (int j = 0; j < 8; ++j) {
        float l0 = (float)plo[i][j], h0 = (float)phi[i][j];
        float v = (float)pt2[i][j] + l0 + pfr[i] * (h0 - l0);
        o[j] = (__bf16)fmaxf(v, 0.f);
      }
      *(bf16x8*)&buf[e * 136 + cg * 8] = o;
    }
  };
  auto mfma_chunk = [&](const u16* buf, int k0, int nk) {
    for (int kk = 0; kk < nk; ++kk) {
      bf16x8 a[4];
#pragma unroll
      for (int m = 0; m < 4; ++m)
        a[m] = *(const bf16x8*)&buf[(m * 16 + ln) * 136 + kk * 32 + q * 8];
#pragma unroll
      for (int n = 0; n < 2; ++n) {
        bf16x8 b = *(const bf16x8*)&We2b[(nb + n * 16 + ln) * 448 + k0 + kk * 32 + q * 8];
#pragma unroll
        for (int m = 0; m < 4; ++m) acc[m][n] = MFMA16(a[m], b, acc[m][n]);
      }
    }
  };

  // pipelined chunk schedule
  {
    bf16x8 plo[4], phi[4], pt2[4]; float pfr[4];
    prefetch128(0, plo, phi, pt2, pfr);
    store128(sC[0], plo, phi, pt2, pfr);
  }
  lds_barrier();
  {
    bf16x8 plo[4], phi[4], pt2[4]; float pfr[4];
    prefetch128(128, plo, phi, pt2, pfr);
    mfma_chunk(sC[0], 0, 4);
    store128(sC[1], plo, phi, pt2, pfr);
  }
  lds_barrier();
  {
    bf16x8 plo[4], phi[4], pt2[4]; float pfr[4];
    prefetch128(256, plo, phi, pt2, pfr);
    mfma_chunk(sC[1], 128, 4);
    store128(sC[0], plo, phi, pt2, pfr);
  }
  lds_barrier();
  bf16x8 nrows[4];  // n2 row staging: unit u = tid + 256*i -> e=u>>4, cg=u&15
  {
    bf16x8 plo[2], phi[2], pt2[2]; float pfr[2];
    prefetch64(plo, phi, pt2, pfr);
    // issue n2 row loads (coalesced 16B, row-contiguous)
#pragma unroll
    for (int i = 0; i < 4; ++i) {
      int u = tid + 256 * i;
      int e = u >> 4, cg = u & 15;
      nrows[i] = *(const bf16x8*)&n2[(size_t)sSrc[e] * 128 + cg * 8];
    }
    mfma_chunk(sC[0], 256, 4);
    store64(sC[1], plo, phi, pt2, pfr);
  }
  lds_barrier();  // sC[0] now free for all waves

  // stage n2 rows into sC[0], then finish last K chunk
  u16* sN = sC[0];
#pragma unroll
  for (int i = 0; i < 4; ++i) {
    int u = tid + 256 * i;
    int e = u >> 4, cg = u & 15;
    *(bf16x8*)&sN[e * 136 + cg * 8] = nrows[i];
  }
  mfma_chunk(sC[1], 384, 2);
  lds_barrier();

  // epilogue 2: P = (EE + be2) * n2[src]  -> sP
  {
    float be2v[2] = {be2[nb + ln], be2[nb + 16 + ln]};
#pragma unroll
    for (int n = 0; n < 2; ++n) {
      int col = nb + n * 16 + ln;
#pragma unroll
      for (int m = 0; m < 4; ++m)
#pragma unroll
        for (int r = 0; r < 4; ++r) {
          int row = m * 16 + q * 4 + r;
          float ee = acc[m][n][r] + be2v[n];
          float v = ee * bf2f(sN[row * 136 + col]);
          *(__bf16*)&sP[row * 136 + col] = (__bf16)v;
        }
    }
  }
  lds_barrier();

  // phase 3: m = tanh(P @ Wc^T + bc); h[dst] += m  (run-merged atomics)
  {
    f32x4 acc2[4][2];
#pragma unroll
    for (int m = 0; m < 4; ++m)
#pragma unroll
      for (int n = 0; n < 2; ++n) acc2[m][n] = 0.f;
#pragma unroll
    for (int k0 = 0; k0 < 128; k0 += 32) {
      bf16x8 a[4];
#pragma unroll
      for (int m = 0; m < 4; ++m)
        a[m] = *(const bf16x8*)&sP[(m * 16 + ln) * 136 + k0 + q * 8];
#pragma unroll
      for (int n = 0; n < 2; ++n) {
        bf16x8 b = *(const bf16x8*)&Wcb[(nb + n * 16 + ln) * 128 + k0 + q * 8];
#pragma unroll
        for (int m = 0; m < 4; ++m) acc2[m][n] = MFMA16(a[m], b, acc2[m][n]);
      }
    }
    float bcv[2] = {bc[nb + ln], bc[nb + 16 + ln]};
#pragma unroll
    for (int m = 0; m < 4; ++m) {
      int d[4];
#pragma unroll
      for (int r = 0; r < 4; ++r) d[r] = sDst[m * 16 + q * 4 + r];
#pragma unroll
      for (int n = 0; n < 2; ++n) {
        int col = nb + n * 16 + ln;
        float t[4];
#pragma unroll
        for (int r = 0; r < 4; ++r) {
          // Pade [3/2] tanh: inputs ~1e-3 scale, err << bf16 ulp
          float x = acc2[m][n][r] + bcv[n];
          x = fminf(2.f, fmaxf(-2.f, x));
          float x2 = x * x;
          t[r] = x * (15.f + x2) * __builtin_amdgcn_rcpf(15.f + 6.f * x2);
        }
        // merge consecutive same-dst runs (edges sorted by dst)
        float s = t[0];
        int cur = d[0];
#pragma unroll
        for (int r = 1; r < 4; ++r) {
          if (d[r] == cur) {
            s += t[r];
          } else {
            unsafeAtomicAdd(&h[(size_t)cur * 128 + col], s);
            cur = d[r];
            s = t[r];
          }
        }
        unsafeAtomicAdd(&h[(size_t)cur * 128 + col], s);
      }
    }
  }
}

// ---------------- readout ----------------

__global__ __launch_bounds__(256) void k_read(const float* __restrict__ h,
                                              const float* __restrict__ Wr1,
                                              const float* __restrict__ br1,
                                              const float* __restrict__ Wr2,
                                              const float* __restrict__ br2,
                                              const int* __restrict__ gid,
                                              float* __restrict__ out) {
  __shared__ __align__(16) u16 sH[64 * 136];
  __shared__ __align__(16) u16 sW[128 * 136];
  __shared__ float sR4[4][64];
  const int tid = threadIdx.x;
  const int nbase = blockIdx.x * 64;
  for (int i = tid; i < 64 * 128; i += 256) {
    int e = i >> 7, d = i & 127;
    int node = nbase + e;
    float v = (node < NN) ? h[(size_t)node * 128 + d] : 0.f;
    sH[e * 136 + d] = f2bf(v);
  }
  for (int i = tid; i < 128 * 128; i += 256) {
    int rr = i >> 7, d = i & 127;
    sW[rr * 136 + d] = f2bf(Wr1[i]);
  }
  __syncthreads();
  const int lane = tid & 63, wave = tid >> 6;
  const int q = lane >> 4, ln = lane & 15;
  const int nb = wave * 32;

  f32x4 acc[4][2];
#pragma unroll
  for (int m = 0; m < 4; ++m)
#pragma unroll
    for (int n = 0; n < 2; ++n) acc[m][n] = 0.f;
#pragma unroll
  for (int k0 = 0; k0 < 128; k0 += 32) {
    bf16x8 a[4];
#pragma unroll
    for (int m = 0; m < 4; ++m)
      a[m] = *(const bf16x8*)&sH[(m * 16 + ln) * 136 + k0 + q * 8];
#pragma unroll
    for (int n = 0; n < 2; ++n) {
      bf16x8 b = *(const bf16x8*)&sW[(nb + n * 16 + ln) * 136 + k0 + q * 8];
#pragma unroll
      for (int m = 0; m < 4; ++m) acc[m][n] = MFMA16(a[m], b, acc[m][n]);
    }
  }
#pragma unroll
  for (int m = 0; m < 4; ++m)
#pragma unroll
    for (int r = 0; r < 4; ++r) {
      float t = 0.f;
#pragma unroll
      for (int n = 0; n < 2; ++n) {
        int col = nb + n * 16 + ln;
        t += fmaxf(acc[m][n][r] + br1[col], 0.f) * Wr2[col];
      }
      t += __shfl_xor(t, 1);
      t += __shfl_xor(t, 2);
      t += __shfl_xor(t, 4);
      t += __shfl_xor(t, 8);
      if (ln == 0) sR4[wave][m * 16 + q * 4 + r] = t;
    }
  __syncthreads();
  if (tid < 64) {
    int node = nbase + tid;
    if (node < NN) {
      float s = sR4[0][tid] + sR4[1][tid] + sR4[2][tid] + sR4[3][tid] + br2[0];
      unsafeAtomicAdd(&out[gid[node]], s);
    }
  }
}

// ---------------- launch ----------------

extern "C" void kernel_launch(void* const* d_in, const int* in_sizes, int n_in,
                              void* d_out, int out_size, void* d_ws, size_t ws_size,
                              hipStream_t stream) {
  const int* Z = (const int*)d_in[0];
  const int* etype = (const int*)d_in[1];
  const float* dist = (const float*)d_in[2];
  const int* src = (const int*)d_in[3];
  const int* dst = (const int*)d_in[4];
  const int* gid = (const int*)d_in[5];
  const float* node_emb = (const float*)d_in[6];
  const float* edge_emb = (const float*)d_in[7];
  const float* Wn1 = (const float*)d_in[8];
  const float* bn1 = (const float*)d_in[9];
  const float* Wn2 = (const float*)d_in[10];
  const float* bn2 = (const float*)d_in[11];
  const float* We1 = (const float*)d_in[12];
  const float* be1 = (const float*)d_in[13];
  const float* We2 = (const float*)d_in[14];
  const float* be2 = (const float*)d_in[15];
  const float* Wc = (const float*)d_in[16];
  const float* bc = (const float*)d_in[17];
  const float* Wr1 = (const float*)d_in[18];
  const float* br1 = (const float*)d_in[19];
  const float* Wr2 = (const float*)d_in[20];
  const float* br2 = (const float*)d_in[21];
  float* out = (float*)d_out;

  char* ws = (char*)d_ws;
  float* h = (float*)(ws);                   // 51,200,000 B
  u16* n2 = (u16*)(ws + 51200000);           // 25,600,000 B
  u16* Rb = (u16*)(ws + 76800000);           //    860,160 B
  u16* We2b = (u16*)(ws + 77660160);         //    344,064 B
  u16* Wcb = (u16*)(ws + 78004224);          //     98,304 B
  u16* Wn1b = (u16*)(ws + 78102528);         //     98,304 B
  u16* Wn2b = (u16*)(ws + 78200832);         //     98,304 B
  u16* T2 = (u16*)(ws + 78299136);           //  1,075,200 B
  u16* Dtab = (u16*)(ws + 79374336);         //  5,507,712 B  -> 84,882,048
  int4* epack = (int4*)(ws + 84882048);      //  6,400,000 B  -> 91,282,048
  int* edst = (int*)(ws + 91282048);         //  1,600,000 B  -> 92,882,048
  u32* hist = (u32*)(ws + 92882048);         //    400,000 B  -> 93,282,048
  u32* cursor = (u32*)(ws + 93282048);       //    400,000 B  -> 93,682,048
  u32* excl = (u32*)(ws + 93682048);         //    400,000 B  -> 94,082,048
  u32* part = (u32*)(ws + 94082048);         //        512 B  -> 94,082,560

  // edge sort by dst (once, reused by all 3 layers)
  k_zero32<<<391, 256, 0, stream>>>(hist, NN);
  k_hist<<<1563, 256, 0, stream>>>(dst, hist);
  k_scan1<<<98, 1024, 0, stream>>>(hist, excl, part);
  k_scan2<<<1, 64, 0, stream>>>(part, 98);
  k_scan3<<<98, 1024, 0, stream>>>(excl, part, cursor);
  k_scatter<<<1563, 256, 0, stream>>>(etype, dist, src, dst, cursor, epack, edst);

  k_convert<<<192, 256, 0, stream>>>(Wn1, Wn1b, 49152);
  k_convert<<<192, 256, 0, stream>>>(Wn2, Wn2b, 49152);
  k_convert<<<192, 256, 0, stream>>>(Wc, Wcb, 49152);
  k_pad_we2<<<672, 256, 0, stream>>>(We2, We2b);
  k_pad_R<<<1680, 256, 0, stream>>>(We1, Rb);
  k_t2<<<2100, 256, 0, stream>>>(edge_emb, We1, be1, T2);
  k_dtab<<<3 * (GRID + 1), 256, 0, stream>>>(Rb, Dtab);
  k_hinit<<<12500, 256, 0, stream>>>(Z, node_emb, h);
  k_zero_out<<<8, 256, 0, stream>>>(out);

  for (int l = 0; l < 3; ++l) {
    k_node<<<1563, 256, 0, stream>>>(h, Wn1b + l * 16384, bn1 + l * 128,
                                     Wn2b + l * 16384, bn2 + l * 128, n2);
    k_edge<<<6250, 256, 0, stream>>>(epack, edst,
                                     T2 + l * 179200, Dtab + (size_t)l * (GRID + 1) * 448,
                                     We2b + l * 57344, be2 + l * 128,
                                     Wcb + l * 16384, bc + l * 128, n2, h);
  }
  k_read<<<1563, 256, 0, stream>>>(h, Wr1, br1, Wr2, br2, gid, out);
}

// Round 6
// 982.849 us; speedup vs baseline: 1.8737x; 1.0352x over previous
//
#include <hip/hip_runtime.h>

#define NN 100000
#define En 400000
#define Gn 2000
#define GRID 2048

typedef unsigned short u16;
typedef unsigned int u32;
typedef __bf16 bf16x8 __attribute__((ext_vector_type(8)));
typedef float f32x4 __attribute__((ext_vector_type(4)));

__device__ __forceinline__ u16 f2bf(float f) {
  union { float f; u32 u; } v; v.f = f;
  return (u16)((v.u + 0x7FFFu + ((v.u >> 16) & 1u)) >> 16);
}
__device__ __forceinline__ float bf2f(u16 h) {
  union { u32 u; float f; } v; v.u = ((u32)h) << 16;
  return v.f;
}

// barrier that drains only LDS ops (global loads/atomics stay in flight)
__device__ __forceinline__ void lds_barrier() {
  asm volatile("s_waitcnt lgkmcnt(0)\ns_barrier" ::: "memory");
}

#define MFMA16(a, b, c) __builtin_amdgcn_mfma_f32_16x16x32_bf16(a, b, c, 0, 0, 0)

// ---------------- prep kernels ----------------

__global__ __launch_bounds__(256) void k_convert(const float* __restrict__ src,
                                                 u16* __restrict__ dst, int n) {
  int i = blockIdx.x * 256 + threadIdx.x;
  if (i < n) dst[i] = f2bf(src[i]);
}

// We2 [3][128][428] -> bf16 padded [3][128][448]
__global__ __launch_bounds__(256) void k_pad_we2(const float* __restrict__ We2,
                                                 u16* __restrict__ dst) {
  int i = blockIdx.x * 256 + threadIdx.x;
  if (i >= 3 * 128 * 448) return;
  int l = i / 57344;
  int r = i - l * 57344;
  int row = r / 448;
  int k = r - row * 448;
  float v = (k < 428) ? We2[l * 54784 + row * 428 + k] : 0.f;
  dst[i] = f2bf(v);
}

// R = We1[:, :, 128:] [3][428][300] -> bf16 padded [3][448][320]
__global__ __launch_bounds__(256) void k_pad_R(const float* __restrict__ We1,
                                               u16* __restrict__ dst) {
  int i = blockIdx.x * 256 + threadIdx.x;
  if (i >= 3 * 448 * 320) return;
  int l = i / 143360;
  int r = i - l * 143360;
  int row = r / 320;
  int k = r - row * 320;
  float v = 0.f;
  if (row < 428 && k < 300) v = We1[(size_t)l * 183184 + row * 428 + 128 + k];
  dst[i] = f2bf(v);
}

// T2[l][t][j] = edge_emb[t]·We1[l][j][:128] + be1[l][j]   bf16 [3][400][448]
__global__ __launch_bounds__(256) void k_t2(const float* __restrict__ edge_emb,
                                            const float* __restrict__ We1,
                                            const float* __restrict__ be1,
                                            u16* __restrict__ T2) {
  int idx = blockIdx.x * 256 + threadIdx.x;
  if (idx >= 3 * 400 * 448) return;
  int l = idx / (400 * 448);
  int r = idx - l * (400 * 448);
  int t = r / 448;
  int j = r - t * 448;
  float s = 0.f;
  if (j < 428) {
    const float4* er = (const float4*)(edge_emb + t * 128);
    const float4* wr = (const float4*)(We1 + (size_t)l * 183184 + j * 428);
#pragma unroll
    for (int d = 0; d < 32; ++d) {
      float4 a = er[d], b = wr[d];
      s += a.x * b.x + a.y * b.y + a.z * b.z + a.w * b.w;
    }
    s += be1[l * 428 + j];
  }
  T2[idx] = f2bf(s);
}

// Dtab[l][g][j] = sum_k rbf_k(g*delta) * R[l][j][k]   bf16 [3][GRID+1][448]
__global__ __launch_bounds__(256) void k_dtab(const u16* __restrict__ Rb,
                                              u16* __restrict__ Dtab) {
  const int tid = threadIdx.x;
  int l = blockIdx.x / (GRID + 1);
  int g = blockIdx.x - l * (GRID + 1);
  float d = (float)g * (30.f / (float)GRID);
  int kc = (int)(d * (299.f / 30.f) + 0.5f);
  int kk0 = min(max(kc - 16, 0), 268);
  __shared__ float sE[32];
  if (tid < 32) {
    float x = d - (float)(kk0 + tid) * (30.f / 299.f);
    sE[tid] = __expf(-x * x * (299.f / 30.f));
  }
  __syncthreads();
  for (int j = tid; j < 448; j += 256) {
    const u16* rr = &Rb[((size_t)l * 448 + j) * 320 + kk0];
    float s = 0.f;
#pragma unroll
    for (int k = 0; k < 32; ++k) s += sE[k] * bf2f(rr[k]);
    Dtab[((size_t)(l * (GRID + 1) + g)) * 448 + j] = f2bf(s);
  }
}

// h[n][:] = node_emb[Z[n]][:]
__global__ __launch_bounds__(256) void k_hinit(const int* __restrict__ Z,
                                               const float* __restrict__ node_emb,
                                               float* __restrict__ h) {
  int idx = blockIdx.x * 256 + threadIdx.x;
  int n = idx >> 5;
  int c = idx & 31;
  ((float4*)h)[idx] = ((const float4*)node_emb)[Z[n] * 32 + c];
}

__global__ __launch_bounds__(256) void k_zero_out(float* __restrict__ out) {
  int i = blockIdx.x * 256 + threadIdx.x;
  if (i < Gn) out[i] = 0.f;
}

// ---------------- counting sort of edges by dst ----------------

__global__ __launch_bounds__(256) void k_zero32(u32* __restrict__ p, int n) {
  int i = blockIdx.x * 256 + threadIdx.x;
  if (i < n) p[i] = 0u;
}

__global__ __launch_bounds__(256) void k_hist(const int* __restrict__ dstv,
                                              u32* __restrict__ hist) {
  int e = blockIdx.x * 256 + threadIdx.x;
  if (e < En) atomicAdd(&hist[dstv[e]], 1u);
}

// inclusive scan per 1024-block; writes exclusive-within-block + block total
__global__ __launch_bounds__(1024) void k_scan1(const u32* __restrict__ hist,
                                                u32* __restrict__ excl,
                                                u32* __restrict__ part) {
  __shared__ u32 s[1024];
  const int t = threadIdx.x, b = blockIdx.x, i = b * 1024 + t;
  u32 v = (i < NN) ? hist[i] : 0u;
  s[t] = v;
  __syncthreads();
  u32 acc = v;
  for (int off = 1; off < 1024; off <<= 1) {
    u32 add = (t >= off) ? s[t - off] : 0u;
    __syncthreads();
    acc += add;
    s[t] = acc;
    __syncthreads();
  }
  if (i < NN) excl[i] = acc - v;
  if (t == 1023) part[b] = acc;
}

// parallel exclusive scan of <=128 block partials
__global__ __launch_bounds__(128) void k_scan2(u32* __restrict__ part, int n) {
  __shared__ u32 s[128];
  const int t = threadIdx.x;
  u32 v = (t < n) ? part[t] : 0u;
  s[t] = v;
  __syncthreads();
  u32 acc = v;
  for (int off = 1; off < 128; off <<= 1) {
    u32 add = (t >= off) ? s[t - off] : 0u;
    __syncthreads();
    acc += add;
    s[t] = acc;
    __syncthreads();
  }
  if (t < n) part[t] = acc - v;
}

__global__ __launch_bounds__(1024) void k_scan3(const u32* __restrict__ excl,
                                                const u32* __restrict__ part,
                                                u32* __restrict__ cursor) {
  int i = blockIdx.x * 1024 + threadIdx.x;
  if (i < NN) cursor[i] = excl[i] + part[blockIdx.x];
}

__global__ __launch_bounds__(256) void k_scatter(const int* __restrict__ etype,
                                                 const float* __restrict__ dist,
                                                 const int* __restrict__ srcv,
                                                 const int* __restrict__ dstv,
                                                 u32* __restrict__ cursor,
                                                 int4* __restrict__ epack,
                                                 int* __restrict__ edst) {
  int e = blockIdx.x * 256 + threadIdx.x;
  if (e >= En) return;
  int d = dstv[e];
  int pos = (int)atomicAdd(&cursor[d], 1u);
  float fi = dist[e] * ((float)GRID / 30.f);
  int ix = (int)fi;
  epack[pos] = make_int4(srcv[e], etype[e] * 448, ix * 448,
                         __float_as_int(fi - (float)ix));
  edst[pos] = d;
}

// ---------------- node MLP: n2 = relu(h@W1^T+b1)@W2^T+b2  (bf16 out) ----------------

__global__ __launch_bounds__(256) void k_node(const float* __restrict__ h,
                                              const u16* __restrict__ W1,
                                              const float* __restrict__ b1,
                                              const u16* __restrict__ W2,
                                              const float* __restrict__ b2,
                                              u16* __restrict__ n2) {
  __shared__ __align__(16) u16 sH[64 * 136];
  __shared__ __align__(16) u16 sT[64 * 136];
  const int tid = threadIdx.x;
  const int nbase = blockIdx.x * 64;
  for (int i = tid; i < 64 * 128; i += 256) {
    int e = i >> 7, d = i & 127;
    int node = nbase + e;
    float v = (node < NN) ? h[(size_t)node * 128 + d] : 0.f;
    sH[e * 136 + d] = f2bf(v);
  }
  lds_barrier();
  const int lane = tid & 63, wave = tid >> 6;
  const int q = lane >> 4, ln = lane & 15;
  const int nb = wave * 32;

  f32x4 acc[4][2];
#pragma unroll
  for (int m = 0; m < 4; ++m)
#pragma unroll
    for (int n = 0; n < 2; ++n) acc[m][n] = 0.f;
#pragma unroll
  for (int k0 = 0; k0 < 128; k0 += 32) {
    bf16x8 a[4];
#pragma unroll
    for (int m = 0; m < 4; ++m)
      a[m] = *(const bf16x8*)&sH[(m * 16 + ln) * 136 + k0 + q * 8];
#pragma unroll
    for (int n = 0; n < 2; ++n) {
      bf16x8 b = *(const bf16x8*)&W1[(nb + n * 16 + ln) * 128 + k0 + q * 8];
#pragma unroll
      for (int m = 0; m < 4; ++m) acc[m][n] = MFMA16(a[m], b, acc[m][n]);
    }
  }
#pragma unroll
  for (int n = 0; n < 2; ++n) {
    int col = nb + n * 16 + ln;
    float bb = b1[col];
#pragma unroll
    for (int m = 0; m < 4; ++m)
#pragma unroll
      for (int r = 0; r < 4; ++r) {
        int row = m * 16 + q * 4 + r;
        sT[row * 136 + col] = f2bf(fmaxf(acc[m][n][r] + bb, 0.f));
      }
  }
  lds_barrier();

  f32x4 acc2[4][2];
#pragma unroll
  for (int m = 0; m < 4; ++m)
#pragma unroll
    for (int n = 0; n < 2; ++n) acc2[m][n] = 0.f;
#pragma unroll
  for (int k0 = 0; k0 < 128; k0 += 32) {
    bf16x8 a[4];
#pragma unroll
    for (int m = 0; m < 4; ++m)
      a[m] = *(const bf16x8*)&sT[(m * 16 + ln) * 136 + k0 + q * 8];
#pragma unroll
    for (int n = 0; n < 2; ++n) {
      bf16x8 b = *(const bf16x8*)&W2[(nb + n * 16 + ln) * 128 + k0 + q * 8];
#pragma unroll
      for (int m = 0; m < 4; ++m) acc2[m][n] = MFMA16(a[m], b, acc2[m][n]);
    }
  }
#pragma unroll
  for (int n = 0; n < 2; ++n) {
    int col = nb + n * 16 + ln;
    float bb = b2[col];
#pragma unroll
    for (int m = 0; m < 4; ++m)
#pragma unroll
      for (int r = 0; r < 4; ++r) {
        int row = m * 16 + q * 4 + r;
        int node = nbase + row;
        if (node < NN) n2[(size_t)node * 128 + col] = f2bf(acc2[m][n][r] + bb);
      }
  }
}

// ---------------- fused edge kernel (one layer) ----------------
// chunked pipeline + dst-sorted edges + LDS n2 staging + run-merged atomics
// sP aliases sC[1] after last K-chunk -> LDS ~36.1 KB -> 4 blocks/CU

__global__ __launch_bounds__(256, 4) void k_edge(
    const int4* __restrict__ epack, const int* __restrict__ edst,
    const u16* __restrict__ T2, const u16* __restrict__ Dtab,
    const u16* __restrict__ We2b, const float* __restrict__ be2,
    const u16* __restrict__ Wcb, const float* __restrict__ bc,
    const u16* __restrict__ n2, float* __restrict__ h) {
  __shared__ __align__(16) u16 sC[2][64 * 136];  // U K-chunks; sC[0] -> n2 rows, sC[1] -> P
  __shared__ int sSrc[64], sDst[64], sT2o[64], sIdx[64];
  __shared__ float sFrac[64];

  const int tid = threadIdx.x;
  const int e0 = blockIdx.x * 64;
  if (tid < 64) {
    int4 p = epack[e0 + tid];
    sSrc[tid] = p.x;
    sT2o[tid] = p.y;
    sIdx[tid] = p.z;
    sFrac[tid] = __int_as_float(p.w);
    sDst[tid] = edst[e0 + tid];
  }
  lds_barrier();

  const int lane = tid & 63, wave = tid >> 6;
  const int q = lane >> 4, ln = lane & 15;
  const int nb = wave * 32;

  f32x4 acc[4][2];
#pragma unroll
  for (int m = 0; m < 4; ++m)
#pragma unroll
    for (int n = 0; n < 2; ++n) acc[m][n] = 0.f;

  auto prefetch128 = [&](int k0, bf16x8* plo, bf16x8* phi, bf16x8* pt2, float* pfr) {
    const int cg = tid & 15, eb = tid >> 4;
    const int col = k0 + cg * 8;
#pragma unroll
    for (int i = 0; i < 4; ++i) {
      int e = eb + i * 16;
      int off = sIdx[e] + col;
      plo[i] = *(const bf16x8*)&Dtab[off];
      phi[i] = *(const bf16x8*)&Dtab[off + 448];
      pt2[i] = *(const bf16x8*)&T2[sT2o[e] + col];
      pfr[i] = sFrac[e];
    }
  };
  auto store128 = [&](u16* buf, const bf16x8* plo, const bf16x8* phi,
                      const bf16x8* pt2, const float* pfr) {
    const int cg = tid & 15, eb = tid >> 4;
#pragma unroll
    for (int i = 0; i < 4; ++i) {
      int e = eb + i * 16;
      bf16x8 o;
#pragma unroll
      for (int j = 0; j < 8; ++j) {
        float l0 = (float)plo[i][j], h0 = (float)phi[i][j];
        float v = (float)pt2[i][j] + l0 + pfr[i] * (h0 - l0);
        o[j] = (__bf16)fmaxf(v, 0.f);
      }
      *(bf16x8*)&buf[e * 136 + cg * 8] = o;
    }
  };
  auto prefetch64 = [&](bf16x8* plo, bf16x8* phi, bf16x8* pt2, float* pfr) {
    const int cg = tid & 7, eb = tid >> 3;
    const int col = 384 + cg * 8;
#pragma unroll
    for (int i = 0; i < 2; ++i) {
      int e = eb + i * 32;
      int off = sIdx[e] + col;
      plo[i] = *(const bf16x8*)&Dtab[off];
      phi[i] = *(const bf16x8*)&Dtab[off + 448];
      pt2[i] = *(const bf16x8*)&T2[sT2o[e] + col];
      pfr[i] = sFrac[e];
    }
  };
  auto store64 = [&](u16* buf, const bf16x8* plo, const bf16x8* phi,
                     const bf16x8* pt2, const float* pfr) {
    const int cg = tid & 7, eb = tid >> 3;
#pragma unroll
    for (int i = 0; i < 2; ++i) {
      int e = eb + i * 32;
      bf16x8 o;
#pragma unroll
      for (int j = 0; j < 8; ++j) {
        float l0 = (float)plo[i][j], h0 = (float)phi[i][j];
        float v = (float)pt2[i][j] + l0 + pfr[i] * (h0 - l0);
        o[j] = (__bf16)fmaxf(v, 0.f);
      }
      *(bf16x8*)&buf[e * 136 + cg * 8] = o;
    }
  };
  auto mfma_chunk = [&](const u16* buf, int k0, int nk) {
    for (int kk = 0; kk < nk; ++kk) {
      bf16x8 a[4];
#pragma unroll
      for (int m = 0; m < 4; ++m)
        a[m] = *(const bf16x8*)&buf[(m * 16 + ln) * 136 + kk * 32 + q * 8];
#pragma unroll
      for (int n = 0; n < 2; ++n) {
        bf16x8 b = *(const bf16x8*)&We2b[(nb + n * 16 + ln) * 448 + k0 + kk * 32 + q * 8];
#pragma unroll
        for (int m = 0; m < 4; ++m) acc[m][n] = MFMA16(a[m], b, acc[m][n]);
      }
    }
  };

  // pipelined chunk schedule
  {
    bf16x8 plo[4], phi[4], pt2[4]; float pfr[4];
    prefetch128(0, plo, phi, pt2, pfr);
    store128(sC[0], plo, phi, pt2, pfr);
  }
  lds_barrier();
  {
    bf16x8 plo[4], phi[4], pt2[4]; float pfr[4];
    prefetch128(128, plo, phi, pt2, pfr);
    mfma_chunk(sC[0], 0, 4);
    store128(sC[1], plo, phi, pt2, pfr);
  }
  lds_barrier();
  {
    bf16x8 plo[4], phi[4], pt2[4]; float pfr[4];
    prefetch128(256, plo, phi, pt2, pfr);
    mfma_chunk(sC[1], 128, 4);
    store128(sC[0], plo, phi, pt2, pfr);
  }
  lds_barrier();
  bf16x8 nrows[4];  // n2 row staging: unit u = tid + 256*i -> e=u>>4, cg=u&15
  {
    bf16x8 plo[2], phi[2], pt2[2]; float pfr[2];
    prefetch64(plo, phi, pt2, pfr);
    // issue n2 row loads (coalesced 16B, row-contiguous)
#pragma unroll
    for (int i = 0; i < 4; ++i) {
      int u = tid + 256 * i;
      int e = u >> 4, cg = u & 15;
      nrows[i] = *(const bf16x8*)&n2[(size_t)sSrc[e] * 128 + cg * 8];
    }
    mfma_chunk(sC[0], 256, 4);
    store64(sC[1], plo, phi, pt2, pfr);
  }
  lds_barrier();  // sC[0] now free for all waves

  // stage n2 rows into sC[0], then finish last K chunk (reads sC[1])
  u16* sN = sC[0];
#pragma unroll
  for (int i = 0; i < 4; ++i) {
    int u = tid + 256 * i;
    int e = u >> 4, cg = u & 15;
    *(bf16x8*)&sN[e * 136 + cg * 8] = nrows[i];
  }
  mfma_chunk(sC[1], 384, 2);
  lds_barrier();  // all waves done with sC[1]; safe to reuse as P

  // epilogue 2: P = (EE + be2) * n2[src]  -> sP (= sC[1])
  u16* sP = sC[1];
  {
    float be2v[2] = {be2[nb + ln], be2[nb + 16 + ln]};
#pragma unroll
    for (int n = 0; n < 2; ++n) {
      int col = nb + n * 16 + ln;
#pragma unroll
      for (int m = 0; m < 4; ++m)
#pragma unroll
        for (int r = 0; r < 4; ++r) {
          int row = m * 16 + q * 4 + r;
          float ee = acc[m][n][r] + be2v[n];
          float v = ee * bf2f(sN[row * 136 + col]);
          *(__bf16*)&sP[row * 136 + col] = (__bf16)v;
        }
    }
  }
  lds_barrier();

  // phase 3: m = tanh(P @ Wc^T + bc); h[dst] += m  (run-merged atomics)
  {
    f32x4 acc2[4][2];
#pragma unroll
    for (int m = 0; m < 4; ++m)
#pragma unroll
      for (int n = 0; n < 2; ++n) acc2[m][n] = 0.f;
#pragma unroll
    for (int k0 = 0; k0 < 128; k0 += 32) {
      bf16x8 a[4];
#pragma unroll
      for (int m = 0; m < 4; ++m)
        a[m] = *(const bf16x8*)&sP[(m * 16 + ln) * 136 + k0 + q * 8];
#pragma unroll
      for (int n = 0; n < 2; ++n) {
        bf16x8 b = *(const bf16x8*)&Wcb[(nb + n * 16 + ln) * 128 + k0 + q * 8];
#pragma unroll
        for (int m = 0; m < 4; ++m) acc2[m][n] = MFMA16(a[m], b, acc2[m][n]);
      }
    }
    float bcv[2] = {bc[nb + ln], bc[nb + 16 + ln]};
#pragma unroll
    for (int m = 0; m < 4; ++m) {
      int d[4];
#pragma unroll
      for (int r = 0; r < 4; ++r) d[r] = sDst[m * 16 + q * 4 + r];
#pragma unroll
      for (int n = 0; n < 2; ++n) {
        int col = nb + n * 16 + ln;
        float t[4];
#pragma unroll
        for (int r = 0; r < 4; ++r) {
          // Pade [3/2] tanh: inputs ~1e-3 scale, err << bf16 ulp
          float x = acc2[m][n][r] + bcv[n];
          x = fminf(2.f, fmaxf(-2.f, x));
          float x2 = x * x;
          t[r] = x * (15.f + x2) * __builtin_amdgcn_rcpf(15.f + 6.f * x2);
        }
        // merge consecutive same-dst runs (edges sorted by dst)
        float s = t[0];
        int cur = d[0];
#pragma unroll
        for (int r = 1; r < 4; ++r) {
          if (d[r] == cur) {
            s += t[r];
          } else {
            unsafeAtomicAdd(&h[(size_t)cur * 128 + col], s);
            cur = d[r];
            s = t[r];
          }
        }
        unsafeAtomicAdd(&h[(size_t)cur * 128 + col], s);
      }
    }
  }
}

// ---------------- readout ----------------

__global__ __launch_bounds__(256) void k_read(const float* __restrict__ h,
                                              const float* __restrict__ Wr1,
                                              const float* __restrict__ br1,
                                              const float* __restrict__ Wr2,
                                              const float* __restrict__ br2,
                                              const int* __restrict__ gid,
                                              float* __restrict__ out) {
  __shared__ __align__(16) u16 sH[64 * 136];
  __shared__ __align__(16) u16 sW[128 * 136];
  __shared__ float sR4[4][64];
  const int tid = threadIdx.x;
  const int nbase = blockIdx.x * 64;
  for (int i = tid; i < 64 * 128; i += 256) {
    int e = i >> 7, d = i & 127;
    int node = nbase + e;
    float v = (node < NN) ? h[(size_t)node * 128 + d] : 0.f;
    sH[e * 136 + d] = f2bf(v);
  }
  for (int i = tid; i < 128 * 128; i += 256) {
    int rr = i >> 7, d = i & 127;
    sW[rr * 136 + d] = f2bf(Wr1[i]);
  }
  lds_barrier();
  const int lane = tid & 63, wave = tid >> 6;
  const int q = lane >> 4, ln = lane & 15;
  const int nb = wave * 32;

  f32x4 acc[4][2];
#pragma unroll
  for (int m = 0; m < 4; ++m)
#pragma unroll
    for (int n = 0; n < 2; ++n) acc[m][n] = 0.f;
#pragma unroll
  for (int k0 = 0; k0 < 128; k0 += 32) {
    bf16x8 a[4];
#pragma unroll
    for (int m = 0; m < 4; ++m)
      a[m] = *(const bf16x8*)&sH[(m * 16 + ln) * 136 + k0 + q * 8];
#pragma unroll
    for (int n = 0; n < 2; ++n) {
      bf16x8 b = *(const bf16x8*)&sW[(nb + n * 16 + ln) * 136 + k0 + q * 8];
#pragma unroll
      for (int m = 0; m < 4; ++m) acc[m][n] = MFMA16(a[m], b, acc[m][n]);
    }
  }
#pragma unroll
  for (int m = 0; m < 4; ++m)
#pragma unroll
    for (int r = 0; r < 4; ++r) {
      float t = 0.f;
#pragma unroll
      for (int n = 0; n < 2; ++n) {
        int col = nb + n * 16 + ln;
        t += fmaxf(acc[m][n][r] + br1[col], 0.f) * Wr2[col];
      }
      t += __shfl_xor(t, 1);
      t += __shfl_xor(t, 2);
      t += __shfl_xor(t, 4);
      t += __shfl_xor(t, 8);
      if (ln == 0) sR4[wave][m * 16 + q * 4 + r] = t;
    }
  lds_barrier();
  if (tid < 64) {
    int node = nbase + tid;
    if (node < NN) {
      float s = sR4[0][tid] + sR4[1][tid] + sR4[2][tid] + sR4[3][tid] + br2[0];
      unsafeAtomicAdd(&out[gid[node]], s);
    }
  }
}

// ---------------- launch ----------------

extern "C" void kernel_launch(void* const* d_in, const int* in_sizes, int n_in,
                              void* d_out, int out_size, void* d_ws, size_t ws_size,
                              hipStream_t stream) {
  const int* Z = (const int*)d_in[0];
  const int* etype = (const int*)d_in[1];
  const float* dist = (const float*)d_in[2];
  const int* src = (const int*)d_in[3];
  const int* dst = (const int*)d_in[4];
  const int* gid = (const int*)d_in[5];
  const float* node_emb = (const float*)d_in[6];
  const float* edge_emb = (const float*)d_in[7];
  const float* Wn1 = (const float*)d_in[8];
  const float* bn1 = (const float*)d_in[9];
  const float* Wn2 = (const float*)d_in[10];
  const float* bn2 = (const float*)d_in[11];
  const float* We1 = (const float*)d_in[12];
  const float* be1 = (const float*)d_in[13];
  const float* We2 = (const float*)d_in[14];
  const float* be2 = (const float*)d_in[15];
  const float* Wc = (const float*)d_in[16];
  const float* bc = (const float*)d_in[17];
  const float* Wr1 = (const float*)d_in[18];
  const float* br1 = (const float*)d_in[19];
  const float* Wr2 = (const float*)d_in[20];
  const float* br2 = (const float*)d_in[21];
  float* out = (float*)d_out;

  char* ws = (char*)d_ws;
  float* h = (float*)(ws);                   // 51,200,000 B
  u16* n2 = (u16*)(ws + 51200000);           // 25,600,000 B
  u16* Rb = (u16*)(ws + 76800000);           //    860,160 B
  u16* We2b = (u16*)(ws + 77660160);         //    344,064 B
  u16* Wcb = (u16*)(ws + 78004224);          //     98,304 B
  u16* Wn1b = (u16*)(ws + 78102528);         //     98,304 B
  u16* Wn2b = (u16*)(ws + 78200832);         //     98,304 B
  u16* T2 = (u16*)(ws + 78299136);           //  1,075,200 B
  u16* Dtab = (u16*)(ws + 79374336);         //  5,507,712 B  -> 84,882,048
  int4* epack = (int4*)(ws + 84882048);      //  6,400,000 B  -> 91,282,048
  int* edst = (int*)(ws + 91282048);         //  1,600,000 B  -> 92,882,048
  u32* hist = (u32*)(ws + 92882048);         //    400,000 B  -> 93,282,048
  u32* cursor = (u32*)(ws + 93282048);       //    400,000 B  -> 93,682,048
  u32* excl = (u32*)(ws + 93682048);         //    400,000 B  -> 94,082,048
  u32* part = (u32*)(ws + 94082048);         //        512 B  -> 94,082,560

  // edge sort by dst (once, reused by all 3 layers)
  k_zero32<<<391, 256, 0, stream>>>(hist, NN);
  k_hist<<<1563, 256, 0, stream>>>(dst, hist);
  k_scan1<<<98, 1024, 0, stream>>>(hist, excl, part);
  k_scan2<<<1, 128, 0, stream>>>(part, 98);
  k_scan3<<<98, 1024, 0, stream>>>(excl, part, cursor);
  k_scatter<<<1563, 256, 0, stream>>>(etype, dist, src, dst, cursor, epack, edst);

  k_convert<<<192, 256, 0, stream>>>(Wn1, Wn1b, 49152);
  k_convert<<<192, 256, 0, stream>>>(Wn2, Wn2b, 49152);
  k_convert<<<192, 256, 0, stream>>>(Wc, Wcb, 49152);
  k_pad_we2<<<672, 256, 0, stream>>>(We2, We2b);
  k_pad_R<<<1680, 256, 0, stream>>>(We1, Rb);
  k_t2<<<2100, 256, 0, stream>>>(edge_emb, We1, be1, T2);
  k_dtab<<<3 * (GRID + 1), 256, 0, stream>>>(Rb, Dtab);
  k_hinit<<<12500, 256, 0, stream>>>(Z, node_emb, h);
  k_zero_out<<<8, 256, 0, stream>>>(out);

  for (int l = 0; l < 3; ++l) {
    k_node<<<1563, 256, 0, stream>>>(h, Wn1b + l * 16384, bn1 + l * 128,
                                     Wn2b + l * 16384, bn2 + l * 128, n2);
    k_edge<<<6250, 256, 0, stream>>>(epack, edst,
                                     T2 + l * 179200, Dtab + (size_t)l * (GRID + 1) * 448,
                                     We2b + l * 57344, be2 + l * 128,
                                     Wcb + l * 16384, bc + l * 128, n2, h);
  }
  k_read<<<1563, 256, 0, stream>>>(h, Wr1, br1, Wr2, br2, gid, out);
}

// Round 7
// 979.127 us; speedup vs baseline: 1.8808x; 1.0038x over previous
//
#include <hip/hip_runtime.h>

#define NN 100000
#define En 400000
#define Gn 2000
#define GRID 2048

typedef unsigned short u16;
typedef unsigned int u32;
typedef _Float16 f16;
typedef f16 f16x8 __attribute__((ext_vector_type(8)));
typedef float f32x4 __attribute__((ext_vector_type(4)));

// barrier that drains only LDS ops (global loads/atomics stay in flight)
__device__ __forceinline__ void lds_barrier() {
  asm volatile("s_waitcnt lgkmcnt(0)\ns_barrier" ::: "memory");
}

#define MFMA16(a, b, c) __builtin_amdgcn_mfma_f32_16x16x32_f16(a, b, c, 0, 0, 0)

// ---------------- prep kernels ----------------

__global__ __launch_bounds__(256) void k_convert(const float* __restrict__ src,
                                                 f16* __restrict__ dst, int n) {
  int i = blockIdx.x * 256 + threadIdx.x;
  if (i < n) dst[i] = (f16)src[i];
}

// We2 [3][128][428] -> f16 padded [3][128][448]
__global__ __launch_bounds__(256) void k_pad_we2(const float* __restrict__ We2,
                                                 f16* __restrict__ dst) {
  int i = blockIdx.x * 256 + threadIdx.x;
  if (i >= 3 * 128 * 448) return;
  int l = i / 57344;
  int r = i - l * 57344;
  int row = r / 448;
  int k = r - row * 448;
  float v = (k < 428) ? We2[l * 54784 + row * 428 + k] : 0.f;
  dst[i] = (f16)v;
}

// R = We1[:, :, 128:] [3][428][300] -> f16 padded [3][448][320]
__global__ __launch_bounds__(256) void k_pad_R(const float* __restrict__ We1,
                                               f16* __restrict__ dst) {
  int i = blockIdx.x * 256 + threadIdx.x;
  if (i >= 3 * 448 * 320) return;
  int l = i / 143360;
  int r = i - l * 143360;
  int row = r / 320;
  int k = r - row * 320;
  float v = 0.f;
  if (row < 428 && k < 300) v = We1[(size_t)l * 183184 + row * 428 + 128 + k];
  dst[i] = (f16)v;
}

// T2[l][t][j] = edge_emb[t]·We1[l][j][:128] + be1[l][j]   f16 [3][400][448]
__global__ __launch_bounds__(256) void k_t2(const float* __restrict__ edge_emb,
                                            const float* __restrict__ We1,
                                            const float* __restrict__ be1,
                                            f16* __restrict__ T2) {
  int idx = blockIdx.x * 256 + threadIdx.x;
  if (idx >= 3 * 400 * 448) return;
  int l = idx / (400 * 448);
  int r = idx - l * (400 * 448);
  int t = r / 448;
  int j = r - t * 448;
  float s = 0.f;
  if (j < 428) {
    const float4* er = (const float4*)(edge_emb + t * 128);
    const float4* wr = (const float4*)(We1 + (size_t)l * 183184 + j * 428);
#pragma unroll
    for (int d = 0; d < 32; ++d) {
      float4 a = er[d], b = wr[d];
      s += a.x * b.x + a.y * b.y + a.z * b.z + a.w * b.w;
    }
    s += be1[l * 428 + j];
  }
  T2[idx] = (f16)s;
}

// Dtab[l][g][j] = sum_k rbf_k(g*delta) * R[l][j][k]   f16 [3][GRID+1][448]
__global__ __launch_bounds__(256) void k_dtab(const f16* __restrict__ Rb,
                                              f16* __restrict__ Dtab) {
  const int tid = threadIdx.x;
  int l = blockIdx.x / (GRID + 1);
  int g = blockIdx.x - l * (GRID + 1);
  float d = (float)g * (30.f / (float)GRID);
  int kc = (int)(d * (299.f / 30.f) + 0.5f);
  int kk0 = min(max(kc - 16, 0), 268);
  __shared__ float sE[32];
  if (tid < 32) {
    float x = d - (float)(kk0 + tid) * (30.f / 299.f);
    sE[tid] = __expf(-x * x * (299.f / 30.f));
  }
  __syncthreads();
  for (int j = tid; j < 448; j += 256) {
    const f16* rr = &Rb[((size_t)l * 448 + j) * 320 + kk0];
    float s = 0.f;
#pragma unroll
    for (int k = 0; k < 32; ++k) s += sE[k] * (float)rr[k];
    Dtab[((size_t)(l * (GRID + 1) + g)) * 448 + j] = (f16)s;
  }
}

// h[n][:] = node_emb[Z[n]][:]
__global__ __launch_bounds__(256) void k_hinit(const int* __restrict__ Z,
                                               const float* __restrict__ node_emb,
                                               float* __restrict__ h) {
  int idx = blockIdx.x * 256 + threadIdx.x;
  int n = idx >> 5;
  int c = idx & 31;
  ((float4*)h)[idx] = ((const float4*)node_emb)[Z[n] * 32 + c];
}

__global__ __launch_bounds__(256) void k_zero_out(float* __restrict__ out) {
  int i = blockIdx.x * 256 + threadIdx.x;
  if (i < Gn) out[i] = 0.f;
}

// ---------------- counting sort of edges by dst ----------------

__global__ __launch_bounds__(256) void k_zero32(u32* __restrict__ p, int n) {
  int i = blockIdx.x * 256 + threadIdx.x;
  if (i < n) p[i] = 0u;
}

__global__ __launch_bounds__(256) void k_hist(const int* __restrict__ dstv,
                                              u32* __restrict__ hist) {
  int e = blockIdx.x * 256 + threadIdx.x;
  if (e < En) atomicAdd(&hist[dstv[e]], 1u);
}

// inclusive scan per 1024-block; writes exclusive-within-block + block total
__global__ __launch_bounds__(1024) void k_scan1(const u32* __restrict__ hist,
                                                u32* __restrict__ excl,
                                                u32* __restrict__ part) {
  __shared__ u32 s[1024];
  const int t = threadIdx.x, b = blockIdx.x, i = b * 1024 + t;
  u32 v = (i < NN) ? hist[i] : 0u;
  s[t] = v;
  __syncthreads();
  u32 acc = v;
  for (int off = 1; off < 1024; off <<= 1) {
    u32 add = (t >= off) ? s[t - off] : 0u;
    __syncthreads();
    acc += add;
    s[t] = acc;
    __syncthreads();
  }
  if (i < NN) excl[i] = acc - v;
  if (t == 1023) part[b] = acc;
}

// parallel exclusive scan of <=128 block partials
__global__ __launch_bounds__(128) void k_scan2(u32* __restrict__ part, int n) {
  __shared__ u32 s[128];
  const int t = threadIdx.x;
  u32 v = (t < n) ? part[t] : 0u;
  s[t] = v;
  __syncthreads();
  u32 acc = v;
  for (int off = 1; off < 128; off <<= 1) {
    u32 add = (t >= off) ? s[t - off] : 0u;
    __syncthreads();
    acc += add;
    s[t] = acc;
    __syncthreads();
  }
  if (t < n) part[t] = acc - v;
}

__global__ __launch_bounds__(1024) void k_scan3(const u32* __restrict__ excl,
                                                const u32* __restrict__ part,
                                                u32* __restrict__ cursor) {
  int i = blockIdx.x * 1024 + threadIdx.x;
  if (i < NN) cursor[i] = excl[i] + part[blockIdx.x];
}

__global__ __launch_bounds__(256) void k_scatter(const int* __restrict__ etype,
                                                 const float* __restrict__ dist,
                                                 const int* __restrict__ srcv,
                                                 const int* __restrict__ dstv,
                                                 u32* __restrict__ cursor,
                                                 int4* __restrict__ epack,
                                                 int* __restrict__ edst) {
  int e = blockIdx.x * 256 + threadIdx.x;
  if (e >= En) return;
  int d = dstv[e];
  int pos = (int)atomicAdd(&cursor[d], 1u);
  float fi = dist[e] * ((float)GRID / 30.f);
  int ix = (int)fi;
  epack[pos] = make_int4(srcv[e], etype[e] * 448, ix * 448,
                         __float_as_int(fi - (float)ix));
  edst[pos] = d;
}

// ---------------- node MLP: n2 = relu(h@W1^T+b1)@W2^T+b2  (f16 out) ----------------

__global__ __launch_bounds__(256) void k_node(const float* __restrict__ h,
                                              const f16* __restrict__ W1,
                                              const float* __restrict__ b1,
                                              const f16* __restrict__ W2,
                                              const float* __restrict__ b2,
                                              f16* __restrict__ n2) {
  __shared__ __align__(16) f16 sH[64 * 136];
  __shared__ __align__(16) f16 sT[64 * 136];
  const int tid = threadIdx.x;
  const int nbase = blockIdx.x * 64;
  for (int i = tid; i < 64 * 128; i += 256) {
    int e = i >> 7, d = i & 127;
    int node = nbase + e;
    float v = (node < NN) ? h[(size_t)node * 128 + d] : 0.f;
    sH[e * 136 + d] = (f16)v;
  }
  lds_barrier();
  const int lane = tid & 63, wave = tid >> 6;
  const int q = lane >> 4, ln = lane & 15;
  const int nb = wave * 32;

  f32x4 acc[4][2];
#pragma unroll
  for (int m = 0; m < 4; ++m)
#pragma unroll
    for (int n = 0; n < 2; ++n) acc[m][n] = 0.f;
#pragma unroll
  for (int k0 = 0; k0 < 128; k0 += 32) {
    f16x8 a[4];
#pragma unroll
    for (int m = 0; m < 4; ++m)
      a[m] = *(const f16x8*)&sH[(m * 16 + ln) * 136 + k0 + q * 8];
#pragma unroll
    for (int n = 0; n < 2; ++n) {
      f16x8 b = *(const f16x8*)&W1[(nb + n * 16 + ln) * 128 + k0 + q * 8];
#pragma unroll
      for (int m = 0; m < 4; ++m) acc[m][n] = MFMA16(a[m], b, acc[m][n]);
    }
  }
#pragma unroll
  for (int n = 0; n < 2; ++n) {
    int col = nb + n * 16 + ln;
    float bb = b1[col];
#pragma unroll
    for (int m = 0; m < 4; ++m)
#pragma unroll
      for (int r = 0; r < 4; ++r) {
        int row = m * 16 + q * 4 + r;
        sT[row * 136 + col] = (f16)fmaxf(acc[m][n][r] + bb, 0.f);
      }
  }
  lds_barrier();

  f32x4 acc2[4][2];
#pragma unroll
  for (int m = 0; m < 4; ++m)
#pragma unroll
    for (int n = 0; n < 2; ++n) acc2[m][n] = 0.f;
#pragma unroll
  for (int k0 = 0; k0 < 128; k0 += 32) {
    f16x8 a[4];
#pragma unroll
    for (int m = 0; m < 4; ++m)
      a[m] = *(const f16x8*)&sT[(m * 16 + ln) * 136 + k0 + q * 8];
#pragma unroll
    for (int n = 0; n < 2; ++n) {
      f16x8 b = *(const f16x8*)&W2[(nb + n * 16 + ln) * 128 + k0 + q * 8];
#pragma unroll
      for (int m = 0; m < 4; ++m) acc2[m][n] = MFMA16(a[m], b, acc2[m][n]);
    }
  }
#pragma unroll
  for (int n = 0; n < 2; ++n) {
    int col = nb + n * 16 + ln;
    float bb = b2[col];
#pragma unroll
    for (int m = 0; m < 4; ++m)
#pragma unroll
      for (int r = 0; r < 4; ++r) {
        int row = m * 16 + q * 4 + r;
        int node = nbase + row;
        if (node < NN) n2[(size_t)node * 128 + col] = (f16)(acc2[m][n][r] + bb);
      }
  }
}

// ---------------- fused edge kernel (one layer) ----------------
// chunked pipeline + dst-sorted edges + LDS n2 staging + run-merged atomics
// fp16 datapath: lerp is packed v_pk_* math, MFMA f16 (same rate as bf16)
// sP aliases sC[1] after last K-chunk -> LDS ~36.1 KB -> 4 blocks/CU

__global__ __launch_bounds__(256, 4) void k_edge(
    const int4* __restrict__ epack, const int* __restrict__ edst,
    const f16* __restrict__ T2, const f16* __restrict__ Dtab,
    const f16* __restrict__ We2b, const float* __restrict__ be2,
    const f16* __restrict__ Wcb, const float* __restrict__ bc,
    const f16* __restrict__ n2, float* __restrict__ h) {
  __shared__ __align__(16) f16 sC[2][64 * 136];  // U K-chunks; sC[0] -> n2 rows, sC[1] -> P
  __shared__ int sSrc[64], sDst[64], sT2o[64], sIdx[64];
  __shared__ float sFrac[64];

  const int tid = threadIdx.x;
  const int e0 = blockIdx.x * 64;
  if (tid < 64) {
    int4 p = epack[e0 + tid];
    sSrc[tid] = p.x;
    sT2o[tid] = p.y;
    sIdx[tid] = p.z;
    sFrac[tid] = __int_as_float(p.w);
    sDst[tid] = edst[e0 + tid];
  }
  lds_barrier();

  const int lane = tid & 63, wave = tid >> 6;
  const int q = lane >> 4, ln = lane & 15;
  const int nb = wave * 32;

  f32x4 acc[4][2];
#pragma unroll
  for (int m = 0; m < 4; ++m)
#pragma unroll
    for (int n = 0; n < 2; ++n) acc[m][n] = 0.f;

  auto lerp_relu = [](f16x8 lo, f16x8 hi, f16x8 t2, f16 fr) -> f16x8 {
    f16x8 v = t2 + lo + (hi - lo) * fr;   // v_pk_add/sub/fma_f16
    f16x8 z = {};
    return __builtin_elementwise_max(v, z);  // v_pk_max_f16
  };

  auto prefetch128 = [&](int k0, f16x8* plo, f16x8* phi, f16x8* pt2, f16* pfr) {
    const int cg = tid & 15, eb = tid >> 4;
    const int col = k0 + cg * 8;
#pragma unroll
    for (int i = 0; i < 4; ++i) {
      int e = eb + i * 16;
      int off = sIdx[e] + col;
      plo[i] = *(const f16x8*)&Dtab[off];
      phi[i] = *(const f16x8*)&Dtab[off + 448];
      pt2[i] = *(const f16x8*)&T2[sT2o[e] + col];
      pfr[i] = (f16)sFrac[e];
    }
  };
  auto store128 = [&](f16* buf, const f16x8* plo, const f16x8* phi,
                      const f16x8* pt2, const f16* pfr) {
    const int cg = tid & 15, eb = tid >> 4;
#pragma unroll
    for (int i = 0; i < 4; ++i) {
      int e = eb + i * 16;
      *(f16x8*)&buf[e * 136 + cg * 8] = lerp_relu(plo[i], phi[i], pt2[i], pfr[i]);
    }
  };
  auto prefetch64 = [&](f16x8* plo, f16x8* phi, f16x8* pt2, f16* pfr) {
    const int cg = tid & 7, eb = tid >> 3;
    const int col = 384 + cg * 8;
#pragma unroll
    for (int i = 0; i < 2; ++i) {
      int e = eb + i * 32;
      int off = sIdx[e] + col;
      plo[i] = *(const f16x8*)&Dtab[off];
      phi[i] = *(const f16x8*)&Dtab[off + 448];
      pt2[i] = *(const f16x8*)&T2[sT2o[e] + col];
      pfr[i] = (f16)sFrac[e];
    }
  };
  auto store64 = [&](f16* buf, const f16x8* plo, const f16x8* phi,
                     const f16x8* pt2, const f16* pfr) {
    const int cg = tid & 7, eb = tid >> 3;
#pragma unroll
    for (int i = 0; i < 2; ++i) {
      int e = eb + i * 32;
      *(f16x8*)&buf[e * 136 + cg * 8] = lerp_relu(plo[i], phi[i], pt2[i], pfr[i]);
    }
  };
  auto mfma_chunk = [&](const f16* buf, int k0, int nk) {
    for (int kk = 0; kk < nk; ++kk) {
      f16x8 a[4];
#pragma unroll
      for (int m = 0; m < 4; ++m)
        a[m] = *(const f16x8*)&buf[(m * 16 + ln) * 136 + kk * 32 + q * 8];
#pragma unroll
      for (int n = 0; n < 2; ++n) {
        f16x8 b = *(const f16x8*)&We2b[(nb + n * 16 + ln) * 448 + k0 + kk * 32 + q * 8];
#pragma unroll
        for (int m = 0; m < 4; ++m) acc[m][n] = MFMA16(a[m], b, acc[m][n]);
      }
    }
  };

  // pipelined chunk schedule
  {
    f16x8 plo[4], phi[4], pt2[4]; f16 pfr[4];
    prefetch128(0, plo, phi, pt2, pfr);
    store128(sC[0], plo, phi, pt2, pfr);
  }
  lds_barrier();
  {
    f16x8 plo[4], phi[4], pt2[4]; f16 pfr[4];
    prefetch128(128, plo, phi, pt2, pfr);
    mfma_chunk(sC[0], 0, 4);
    store128(sC[1], plo, phi, pt2, pfr);
  }
  lds_barrier();
  {
    f16x8 plo[4], phi[4], pt2[4]; f16 pfr[4];
    prefetch128(256, plo, phi, pt2, pfr);
    mfma_chunk(sC[1], 128, 4);
    store128(sC[0], plo, phi, pt2, pfr);
  }
  lds_barrier();
  f16x8 nrows[4];  // n2 row staging: unit u = tid + 256*i -> e=u>>4, cg=u&15
  {
    f16x8 plo[2], phi[2], pt2[2]; f16 pfr[2];
    prefetch64(plo, phi, pt2, pfr);
    // issue n2 row loads (coalesced 16B, row-contiguous)
#pragma unroll
    for (int i = 0; i < 4; ++i) {
      int u = tid + 256 * i;
      int e = u >> 4, cg = u & 15;
      nrows[i] = *(const f16x8*)&n2[(size_t)sSrc[e] * 128 + cg * 8];
    }
    mfma_chunk(sC[0], 256, 4);
    store64(sC[1], plo, phi, pt2, pfr);
  }
  lds_barrier();  // sC[0] now free for all waves

  // stage n2 rows into sC[0], then finish last K chunk (reads sC[1])
  f16* sN = sC[0];
#pragma unroll
  for (int i = 0; i < 4; ++i) {
    int u = tid + 256 * i;
    int e = u >> 4, cg = u & 15;
    *(f16x8*)&sN[e * 136 + cg * 8] = nrows[i];
  }
  mfma_chunk(sC[1], 384, 2);
  lds_barrier();  // all waves done with sC[1]; safe to reuse as P

  // epilogue 2: P = (EE + be2) * n2[src]  -> sP (= sC[1])
  f16* sP = sC[1];
  {
    float be2v[2] = {be2[nb + ln], be2[nb + 16 + ln]};
#pragma unroll
    for (int n = 0; n < 2; ++n) {
      int col = nb + n * 16 + ln;
#pragma unroll
      for (int m = 0; m < 4; ++m)
#pragma unroll
        for (int r = 0; r < 4; ++r) {
          int row = m * 16 + q * 4 + r;
          float ee = acc[m][n][r] + be2v[n];
          float v = ee * (float)sN[row * 136 + col];
          sP[row * 136 + col] = (f16)v;
        }
    }
  }
  lds_barrier();

  // phase 3: m = tanh(P @ Wc^T + bc); h[dst] += m  (run-merged atomics)
  {
    f32x4 acc2[4][2];
#pragma unroll
    for (int m = 0; m < 4; ++m)
#pragma unroll
      for (int n = 0; n < 2; ++n) acc2[m][n] = 0.f;
#pragma unroll
    for (int k0 = 0; k0 < 128; k0 += 32) {
      f16x8 a[4];
#pragma unroll
      for (int m = 0; m < 4; ++m)
        a[m] = *(const f16x8*)&sP[(m * 16 + ln) * 136 + k0 + q * 8];
#pragma unroll
      for (int n = 0; n < 2; ++n) {
        f16x8 b = *(const f16x8*)&Wcb[(nb + n * 16 + ln) * 128 + k0 + q * 8];
#pragma unroll
        for (int m = 0; m < 4; ++m) acc2[m][n] = MFMA16(a[m], b, acc2[m][n]);
      }
    }
    float bcv[2] = {bc[nb + ln], bc[nb + 16 + ln]};
#pragma unroll
    for (int m = 0; m < 4; ++m) {
      int d[4];
#pragma unroll
      for (int r = 0; r < 4; ++r) d[r] = sDst[m * 16 + q * 4 + r];
#pragma unroll
      for (int n = 0; n < 2; ++n) {
        int col = nb + n * 16 + ln;
        float t[4];
#pragma unroll
        for (int r = 0; r < 4; ++r) {
          // Pade [3/2] tanh: inputs ~1e-3 scale, err << f16 ulp
          float x = acc2[m][n][r] + bcv[n];
          x = fminf(2.f, fmaxf(-2.f, x));
          float x2 = x * x;
          t[r] = x * (15.f + x2) * __builtin_amdgcn_rcpf(15.f + 6.f * x2);
        }
        // merge consecutive same-dst runs (edges sorted by dst)
        float s = t[0];
        int cur = d[0];
#pragma unroll
        for (int r = 1; r < 4; ++r) {
          if (d[r] == cur) {
            s += t[r];
          } else {
            unsafeAtomicAdd(&h[(size_t)cur * 128 + col], s);
            cur = d[r];
            s = t[r];
          }
        }
        unsafeAtomicAdd(&h[(size_t)cur * 128 + col], s);
      }
    }
  }
}

// ---------------- readout ----------------

__global__ __launch_bounds__(256) void k_read(const float* __restrict__ h,
                                              const float* __restrict__ Wr1,
                                              const float* __restrict__ br1,
                                              const float* __restrict__ Wr2,
                                              const float* __restrict__ br2,
                                              const int* __restrict__ gid,
                                              float* __restrict__ out) {
  __shared__ __align__(16) f16 sH[64 * 136];
  __shared__ __align__(16) f16 sW[128 * 136];
  __shared__ float sR4[4][64];
  const int tid = threadIdx.x;
  const int nbase = blockIdx.x * 64;
  for (int i = tid; i < 64 * 128; i += 256) {
    int e = i >> 7, d = i & 127;
    int node = nbase + e;
    float v = (node < NN) ? h[(size_t)node * 128 + d] : 0.f;
    sH[e * 136 + d] = (f16)v;
  }
  for (int i = tid; i < 128 * 128; i += 256) {
    int rr = i >> 7, d = i & 127;
    sW[rr * 136 + d] = (f16)Wr1[i];
  }
  lds_barrier();
  const int lane = tid & 63, wave = tid >> 6;
  const int q = lane >> 4, ln = lane & 15;
  const int nb = wave * 32;

  f32x4 acc[4][2];
#pragma unroll
  for (int m = 0; m < 4; ++m)
#pragma unroll
    for (int n = 0; n < 2; ++n) acc[m][n] = 0.f;
#pragma unroll
  for (int k0 = 0; k0 < 128; k0 += 32) {
    f16x8 a[4];
#pragma unroll
    for (int m = 0; m < 4; ++m)
      a[m] = *(const f16x8*)&sH[(m * 16 + ln) * 136 + k0 + q * 8];
#pragma unroll
    for (int n = 0; n < 2; ++n) {
      f16x8 b = *(const f16x8*)&sW[(nb + n * 16 + ln) * 136 + k0 + q * 8];
#pragma unroll
      for (int m = 0; m < 4; ++m) acc[m][n] = MFMA16(a[m], b, acc[m][n]);
    }
  }
#pragma unroll
  for (int m = 0; m < 4; ++m)
#pragma unroll
    for (int r = 0; r < 4; ++r) {
      float t = 0.f;
#pragma unroll
      for (int n = 0; n < 2; ++n) {
        int col = nb + n * 16 + ln;
        t += fmaxf(acc[m][n][r] + br1[col], 0.f) * Wr2[col];
      }
      t += __shfl_xor(t, 1);
      t += __shfl_xor(t, 2);
      t += __shfl_xor(t, 4);
      t += __shfl_xor(t, 8);
      if (ln == 0) sR4[wave][m * 16 + q * 4 + r] = t;
    }
  lds_barrier();
  if (tid < 64) {
    int node = nbase + tid;
    if (node < NN) {
      float s = sR4[0][tid] + sR4[1][tid] + sR4[2][tid] + sR4[3][tid] + br2[0];
      unsafeAtomicAdd(&out[gid[node]], s);
    }
  }
}

// ---------------- launch ----------------

extern "C" void kernel_launch(void* const* d_in, const int* in_sizes, int n_in,
                              void* d_out, int out_size, void* d_ws, size_t ws_size,
                              hipStream_t stream) {
  const int* Z = (const int*)d_in[0];
  const int* etype = (const int*)d_in[1];
  const float* dist = (const float*)d_in[2];
  const int* src = (const int*)d_in[3];
  const int* dst = (const int*)d_in[4];
  const int* gid = (const int*)d_in[5];
  const float* node_emb = (const float*)d_in[6];
  const float* edge_emb = (const float*)d_in[7];
  const float* Wn1 = (const float*)d_in[8];
  const float* bn1 = (const float*)d_in[9];
  const float* Wn2 = (const float*)d_in[10];
  const float* bn2 = (const float*)d_in[11];
  const float* We1 = (const float*)d_in[12];
  const float* be1 = (const float*)d_in[13];
  const float* We2 = (const float*)d_in[14];
  const float* be2 = (const float*)d_in[15];
  const float* Wc = (const float*)d_in[16];
  const float* bc = (const float*)d_in[17];
  const float* Wr1 = (const float*)d_in[18];
  const float* br1 = (const float*)d_in[19];
  const float* Wr2 = (const float*)d_in[20];
  const float* br2 = (const float*)d_in[21];
  float* out = (float*)d_out;

  char* ws = (char*)d_ws;
  float* h = (float*)(ws);                   // 51,200,000 B
  f16* n2 = (f16*)(ws + 51200000);           // 25,600,000 B
  f16* Rb = (f16*)(ws + 76800000);           //    860,160 B
  f16* We2b = (f16*)(ws + 77660160);         //    344,064 B
  f16* Wcb = (f16*)(ws + 78004224);          //     98,304 B
  f16* Wn1b = (f16*)(ws + 78102528);         //     98,304 B
  f16* Wn2b = (f16*)(ws + 78200832);         //     98,304 B
  f16* T2 = (f16*)(ws + 78299136);           //  1,075,200 B
  f16* Dtab = (f16*)(ws + 79374336);         //  5,507,712 B  -> 84,882,048
  int4* epack = (int4*)(ws + 84882048);      //  6,400,000 B  -> 91,282,048
  int* edst = (int*)(ws + 91282048);         //  1,600,000 B  -> 92,882,048
  u32* hist = (u32*)(ws + 92882048);         //    400,000 B  -> 93,282,048
  u32* cursor = (u32*)(ws + 93282048);       //    400,000 B  -> 93,682,048
  u32* excl = (u32*)(ws + 93682048);         //    400,000 B  -> 94,082,048
  u32* part = (u32*)(ws + 94082048);         //        512 B  -> 94,082,560

  // edge sort by dst (once, reused by all 3 layers)
  k_zero32<<<391, 256, 0, stream>>>(hist, NN);
  k_hist<<<1563, 256, 0, stream>>>(dst, hist);
  k_scan1<<<98, 1024, 0, stream>>>(hist, excl, part);
  k_scan2<<<1, 128, 0, stream>>>(part, 98);
  k_scan3<<<98, 1024, 0, stream>>>(excl, part, cursor);
  k_scatter<<<1563, 256, 0, stream>>>(etype, dist, src, dst, cursor, epack, edst);

  k_convert<<<192, 256, 0, stream>>>(Wn1, Wn1b, 49152);
  k_convert<<<192, 256, 0, stream>>>(Wn2, Wn2b, 49152);
  k_convert<<<192, 256, 0, stream>>>(Wc, Wcb, 49152);
  k_pad_we2<<<672, 256, 0, stream>>>(We2, We2b);
  k_pad_R<<<1680, 256, 0, stream>>>(We1, Rb);
  k_t2<<<2100, 256, 0, stream>>>(edge_emb, We1, be1, T2);
  k_dtab<<<3 * (GRID + 1), 256, 0, stream>>>(Rb, Dtab);
  k_hinit<<<12500, 256, 0, stream>>>(Z, node_emb, h);
  k_zero_out<<<8, 256, 0, stream>>>(out);

  for (int l = 0; l < 3; ++l) {
    k_node<<<1563, 256, 0, stream>>>(h, Wn1b + l * 16384, bn1 + l * 128,
                                     Wn2b + l * 16384, bn2 + l * 128, n2);
    k_edge<<<6250, 256, 0, stream>>>(epack, edst,
                                     T2 + l * 179200, Dtab + (size_t)l * (GRID + 1) * 448,
                                     We2b + l * 57344, be2 + l * 128,
                                     Wcb + l * 16384, bc + l * 128, n2, h);
  }
  k_read<<<1563, 256, 0, stream>>>(h, Wr1, br1, Wr2, br2, gid, out);
}